// Round 1
// baseline (991.540 us; speedup 1.0000x reference)
//
#include <hip/hip_runtime.h>
#include <hip/hip_bf16.h>

#define N_NODES 50000
#define N_EDGES 200000
#define IN_F 128
#define HEADS 4
#define FD 64
#define HF 256                      // HEADS*FD
#define NROWS (N_NODES * HEADS)     // 200000 (node,head) rows

// ---------------------------------------------------------------------------
// K1: proj[n][o] = sum_c in[n][c] * Wp[o][c]   (N x 128) @ (256 x 128)^T
// Tile: 32 nodes per block, 256 threads (thread o owns output column o).
// ---------------------------------------------------------------------------
__global__ __launch_bounds__(256) void k_proj(const float* __restrict__ in,
                                              const float* __restrict__ Wp,
                                              float* __restrict__ proj) {
    __shared__ float in_lds[32 * IN_F];
    const int node0 = blockIdx.x * 32;
    const int tid = threadIdx.x;
    const int nvalid = min(32, N_NODES - node0);

    const float4* src = reinterpret_cast<const float4*>(in + (size_t)node0 * IN_F);
    float4* dst = reinterpret_cast<float4*>(in_lds);
    for (int q = tid; q < 32 * IN_F / 4; q += 256) {
        int row = q / (IN_F / 4);
        float4 v = {0.f, 0.f, 0.f, 0.f};
        if (row < nvalid) v = src[q];
        dst[q] = v;
    }
    __syncthreads();

    const int o = tid;
    float acc[32];
#pragma unroll
    for (int n = 0; n < 32; ++n) acc[n] = 0.f;

    const float4* wrow = reinterpret_cast<const float4*>(Wp + (size_t)o * IN_F);
    for (int c4 = 0; c4 < IN_F / 4; ++c4) {
        float4 w = wrow[c4];
#pragma unroll
        for (int n = 0; n < 32; ++n) {
            float4 iv = dst[n * (IN_F / 4) + c4];   // LDS broadcast
            acc[n] += iv.x * w.x + iv.y * w.y + iv.z * w.z + iv.w * w.w;
        }
    }
    for (int n = 0; n < nvalid; ++n)
        proj[(size_t)(node0 + n) * HF + o] = acc[n];
}

// ---------------------------------------------------------------------------
// K2: five 64x64 matvecs per (node,head) row of proj ->
//     tables u1,u2,u3 (att_W1 column blocks), v1,v2 (e_W1 column blocks), bf16.
// 320 threads: thread = (table t in 0..4, output g in 0..63). 32 rows/block.
// ---------------------------------------------------------------------------
__global__ __launch_bounds__(320) void k_uv(const float* __restrict__ proj,
                                            const float* __restrict__ attW1,
                                            const float* __restrict__ eW1,
                                            __hip_bfloat16* __restrict__ tabs) {
    __shared__ float p_lds[32 * FD];
    const int row0 = blockIdx.x * 32;   // NROWS % 32 == 0
    const int tid = threadIdx.x;

    const float4* src = reinterpret_cast<const float4*>(proj + (size_t)row0 * FD);
    float4* dst = reinterpret_cast<float4*>(p_lds);
    for (int q = tid; q < 32 * FD / 4; q += 320) dst[q] = src[q];
    __syncthreads();

    const int t = tid >> 6;
    const int g = tid & 63;
    const float* wrow;
    if (t == 0)      wrow = attW1 + g * 192;          // u1: att_W1[:, 0:64]
    else if (t == 1) wrow = attW1 + g * 192 + 64;     // u2
    else if (t == 2) wrow = attW1 + g * 192 + 128;    // u3
    else if (t == 3) wrow = eW1 + g * 128;            // v1: e_W1[:, 0:64]
    else             wrow = eW1 + g * 128 + 64;       // v2

    float acc[32];
#pragma unroll
    for (int r = 0; r < 32; ++r) acc[r] = 0.f;

    const float4* w4p = reinterpret_cast<const float4*>(wrow);
    for (int f4 = 0; f4 < FD / 4; ++f4) {
        float4 w = w4p[f4];
#pragma unroll
        for (int r = 0; r < 32; ++r) {
            float4 pv = dst[r * (FD / 4) + f4];     // LDS broadcast
            acc[r] += pv.x * w.x + pv.y * w.y + pv.z * w.z + pv.w * w.w;
        }
    }
    __hip_bfloat16* outt = tabs + (size_t)t * NROWS * FD;
    for (int r = 0; r < 32; ++r)
        outt[(size_t)(row0 + r) * FD + g] = __float2bfloat16(acc[r]);
}

// ---------------------------------------------------------------------------
// K3: per-edge kernel. One wave per edge (grid-stride). Lane = feature.
//   scores -> softmax over heads -> 3 second-layer matvecs/head -> atomicAdd.
// e_W2 row held per-lane in 64 VGPRs; g exchanged via per-wave LDS region.
// ---------------------------------------------------------------------------
__global__ __launch_bounds__(256) void k_edge(
        const int* __restrict__ eidx,
        const __hip_bfloat16* __restrict__ u1, const __hip_bfloat16* __restrict__ u2,
        const __hip_bfloat16* __restrict__ u3, const __hip_bfloat16* __restrict__ v1,
        const __hip_bfloat16* __restrict__ v2,
        const float* __restrict__ attb1, const float* __restrict__ attW2,
        const float* __restrict__ attb2, const float* __restrict__ eb1,
        const float* __restrict__ eW2, const float* __restrict__ eb2,
        float* __restrict__ out, int n_wave_total) {
    __shared__ float g_lds[4][3][FD];
    const int lane = threadIdx.x & 63;
    const int wv = threadIdx.x >> 6;
    const int wgid = blockIdx.x * 4 + wv;

    // lane q caches e_W2 row q (64 f32 VGPRs, static indexing only)
    float w2r[FD];
    {
        const float4* w4 = reinterpret_cast<const float4*>(eW2 + lane * FD);
#pragma unroll
        for (int f4 = 0; f4 < FD / 4; ++f4) {
            float4 w = w4[f4];
            w2r[f4 * 4 + 0] = w.x; w2r[f4 * 4 + 1] = w.y;
            w2r[f4 * 4 + 2] = w.z; w2r[f4 * 4 + 3] = w.w;
        }
    }
    const float ab1v = attb1[lane];
    const float aw2v = attW2[lane];
    const float ab2s = attb2[0];
    const float eb1v = eb1[lane];
    const float eb2v = eb2[lane];

    for (int e = wgid; e < N_EDGES; e += n_wave_total) {
        const int ni = eidx[e];
        const int nj = eidx[N_EDGES + e];
        const int nk = eidx[2 * N_EDGES + e];

        // ---- attention scores per head ----
        float s[HEADS];
#pragma unroll
        for (int h = 0; h < HEADS; ++h) {
            float a = __bfloat162float(u1[(size_t)(ni * HEADS + h) * FD + lane]);
            float b = __bfloat162float(u2[(size_t)(nj * HEADS + h) * FD + lane]);
            float c = __bfloat162float(u3[(size_t)(nk * HEADS + h) * FD + lane]);
            float h1 = a + b + c + ab1v;
            h1 = h1 > 0.f ? h1 : 0.f;                 // relu
            float p = aw2v * h1;
#pragma unroll
            for (int m = 1; m < 64; m <<= 1) p += __shfl_xor(p, m);
            float sc = p + ab2s;
            s[h] = sc >= 0.f ? sc : 0.2f * sc;        // leaky 0.2
        }
        // ---- softmax over 4 heads (replicated in every lane) ----
        float mx = fmaxf(fmaxf(s[0], s[1]), fmaxf(s[2], s[3]));
        float att[HEADS];
        float ssum = 0.f;
#pragma unroll
        for (int h = 0; h < HEADS; ++h) { att[h] = expf(s[h] - mx); ssum += att[h]; }
        const float rs = 1.f / ssum;
#pragma unroll
        for (int h = 0; h < HEADS; ++h) att[h] *= rs;

        // ---- second layers + scatter ----
#pragma unroll
        for (int h = 0; h < HEADS; ++h) {
            const size_t ri = (size_t)(ni * HEADS + h) * FD + lane;
            const size_t rj = (size_t)(nj * HEADS + h) * FD + lane;
            const size_t rk = (size_t)(nk * HEADS + h) * FD + lane;
            float v1i = __bfloat162float(v1[ri]);
            float v1j = __bfloat162float(v1[rj]);
            float v2j = __bfloat162float(v2[rj]);
            float v2k = __bfloat162float(v2[rk]);
            float g0 = v1j + v2k + eb1v; g0 = g0 > 0.f ? g0 : 0.2f * g0;  // (pj,pk)
            float g1 = v1i + v2k + eb1v; g1 = g1 > 0.f ? g1 : 0.2f * g1;  // (pi,pk)
            float g2 = v1i + v2j + eb1v; g2 = g2 > 0.f ? g2 : 0.2f * g2;  // (pi,pj)
            g_lds[wv][0][lane] = g0;
            g_lds[wv][1][lane] = g1;
            g_lds[wv][2][lane] = g2;
            // same-wave LDS RAW: compiler orders ds ops (cannot disprove alias)
#pragma unroll
            for (int t = 0; t < 3; ++t) {
                const float4* gb4 = reinterpret_cast<const float4*>(g_lds[wv][t]);
                float pr = eb2v;
#pragma unroll
                for (int f4 = 0; f4 < FD / 4; ++f4) {
                    float4 gv = gb4[f4];                 // broadcast read
                    pr += w2r[f4 * 4 + 0] * gv.x + w2r[f4 * 4 + 1] * gv.y
                        + w2r[f4 * 4 + 2] * gv.z + w2r[f4 * 4 + 3] * gv.w;
                }
                const int nt = (t == 0) ? ni : (t == 1 ? nj : nk);
                atomicAdd(&out[((size_t)t * N_NODES + nt) * HF + h * FD + lane],
                          att[h] * pr);
            }
        }
    }
}

// ---------------------------------------------------------------------------
// K4: out = elu(theta*proj + segsum + bias), in place over [3N, 256]
// ---------------------------------------------------------------------------
__global__ __launch_bounds__(256) void k_final(const float* __restrict__ proj,
                                               const float* __restrict__ theta,
                                               const float* __restrict__ bias,
                                               float* __restrict__ out) {
    const size_t gid = (size_t)blockIdx.x * 256 + threadIdx.x;
    const int hf = (int)(gid & (HF - 1));
    const size_t row = gid >> 8;                 // 0 .. 3N-1
    const int n = (int)(row % N_NODES);
    float val = theta[hf] * proj[(size_t)n * HF + hf] + out[gid] + bias[hf];
    out[gid] = val > 0.f ? val : expm1f(val);
}

// ---------------------------------------------------------------------------
extern "C" void kernel_launch(void* const* d_in, const int* in_sizes, int n_in,
                              void* d_out, int out_size, void* d_ws, size_t ws_size,
                              hipStream_t stream) {
    const float* in_nodes = (const float*)d_in[0];
    const int*   eidx     = (const int*)d_in[1];
    const float* Wp       = (const float*)d_in[2];
    const float* attW1    = (const float*)d_in[3];
    const float* attb1    = (const float*)d_in[4];
    const float* attW2    = (const float*)d_in[5];
    const float* attb2    = (const float*)d_in[6];
    const float* eW1      = (const float*)d_in[7];
    const float* eb1      = (const float*)d_in[8];
    const float* eW2      = (const float*)d_in[9];
    const float* eb2      = (const float*)d_in[10];
    const float* theta    = (const float*)d_in[11];
    const float* bias     = (const float*)d_in[12];

    float* proj = (float*)d_ws;                                   // 51.2 MB f32
    __hip_bfloat16* tabs =
        (__hip_bfloat16*)((char*)d_ws + (size_t)N_NODES * HF * 4); // 5 x 25.6 MB bf16

    float* out = (float*)d_out;

    hipMemsetAsync(d_out, 0, (size_t)out_size * sizeof(float), stream);

    k_proj<<<(N_NODES + 31) / 32, 256, 0, stream>>>(in_nodes, Wp, proj);
    k_uv<<<NROWS / 32, 320, 0, stream>>>(proj, attW1, eW1, tabs);

    const int eblocks = 4096;
    k_edge<<<eblocks, 256, 0, stream>>>(eidx,
        tabs,                         tabs + (size_t)NROWS * FD,
        tabs + 2 * (size_t)NROWS * FD, tabs + 3 * (size_t)NROWS * FD,
        tabs + 4 * (size_t)NROWS * FD,
        attb1, attW2, attb2, eb1, eW2, eb2, out, eblocks * 4);

    k_final<<<3 * N_NODES, 256, 0, stream>>>(proj, theta, bias, out);
}

// Round 2
// 685.011 us; speedup vs baseline: 1.4475x; 1.4475x over previous
//
#include <hip/hip_runtime.h>
#include <hip/hip_bf16.h>

#define N_NODES 50000
#define N_EDGES 200000
#define IN_F 128
#define HEADS 4
#define FD 64
#define HF 256
#define NROWS (N_NODES * HEADS)
#define NCOLS 1536                 // 256 proj cols + 5*256 table cols
#define NTILES (N_EDGES / 16)      // 12500, exact
#define TSZ ((size_t)NROWS * FD)   // elems per table

typedef __attribute__((ext_vector_type(8))) short short8;
typedef __attribute__((ext_vector_type(4))) float f32x4;

__device__ inline short bf16_of(float x) {
    __hip_bfloat16 h = __float2bfloat16(x);
    return *reinterpret_cast<short*>(&h);
}
__device__ inline short8 pack8(float4 a, float4 b) {
    short8 o;
    o[0] = bf16_of(a.x); o[1] = bf16_of(a.y); o[2] = bf16_of(a.z); o[3] = bf16_of(a.w);
    o[4] = bf16_of(b.x); o[5] = bf16_of(b.y); o[6] = bf16_of(b.z); o[7] = bf16_of(b.w);
    return o;
}
__device__ inline void unpk(uint4 v, float* f) {
    f[0] = __uint_as_float(v.x << 16); f[1] = __uint_as_float(v.x & 0xffff0000u);
    f[2] = __uint_as_float(v.y << 16); f[3] = __uint_as_float(v.y & 0xffff0000u);
    f[4] = __uint_as_float(v.z << 16); f[5] = __uint_as_float(v.z & 0xffff0000u);
    f[6] = __uint_as_float(v.w << 16); f[7] = __uint_as_float(v.w & 0xffff0000u);
}
// g = leakyrelu(a + b, 0.2), packed to an MFMA A-fragment chunk
__device__ inline short8 gpack(uint4 ua, uint4 ub) {
    float fa[8], fb[8]; unpk(ua, fa); unpk(ub, fb);
    short8 o;
#pragma unroll
    for (int j = 0; j < 8; ++j) {
        float x = fa[j] + fb[j];
        x = fmaxf(x, 0.2f * x);
        o[j] = bf16_of(x);
    }
    return o;
}
__device__ inline float score8(uint4 ua, uint4 ub, uint4 uc, const float* w) {
    float fa[8], fb[8], fc[8]; unpk(ua, fa); unpk(ub, fb); unpk(uc, fc);
    float p = 0.f;
#pragma unroll
    for (int j = 0; j < 8; ++j) {
        float x = fa[j] + fb[j] + fc[j];
        x = fmaxf(x, 0.f);
        p = fmaf(x, w[j], p);
    }
    return p;
}

// ---------------------------------------------------------------------------
// K0: compose weights. col space c: [0,256) = W_proj rows; [256,1536) =
// table t=(c-256)/256, head h, out g: W_comp[c][k] = sum_f T_t[g][f]*Wp[h*64+f][k].
// Written pre-swizzled into MFMA B-frag layout. Also emits colbias (ab1/eb1 fold).
// ---------------------------------------------------------------------------
__global__ __launch_bounds__(128) void k_comp(const float* __restrict__ Wp,
                                              const float* __restrict__ attW1,
                                              const float* __restrict__ eW1,
                                              const float* __restrict__ attb1,
                                              const float* __restrict__ eb1,
                                              __hip_bfloat16* __restrict__ Bsw,
                                              float* __restrict__ colbias) {
    const int c = blockIdx.x;
    const int k = threadIdx.x;
    float acc;
    float cb = 0.f;
    if (c < HF) {
        acc = Wp[c * IN_F + k];
    } else {
        const int t = (c - HF) >> 8;
        const int rem = (c - HF) & 255;
        const int h = rem >> 6, g = rem & 63;
        const float* T;
        if (t == 0)      T = attW1 + g * 192;
        else if (t == 1) T = attW1 + g * 192 + 64;
        else if (t == 2) T = attW1 + g * 192 + 128;
        else if (t == 3) T = eW1 + g * 128;
        else             T = eW1 + g * 128 + 64;
        acc = 0.f;
        for (int f = 0; f < 64; ++f)
            acc += T[f] * Wp[(h * 64 + f) * IN_F + k];
        if (t == 0) cb = attb1[g];
        else if (t == 3) cb = eb1[g];
    }
    // B-frag layout: frag (ct,ks), lane l = (c%16)+16*((k%32)/8), elem j = k%8
    const int ct = c >> 4, cin = c & 15, ks = k >> 5, kin = k & 31, j = k & 7;
    const int l = cin + ((kin >> 3) << 4);
    Bsw[((ct * 4 + ks) * 64 + l) * 8 + j] = __float2bfloat16(acc);
    if (k == 0) colbias[c] = cb;
}

// ---------------------------------------------------------------------------
// K1: [50000 x 128] @ [128 x 1536] MFMA GEMM -> proj (f32) + 5 bf16 tables.
// Block = 16 rows, 4 waves; wave w owns cols [w*384, w*384+384).
// ---------------------------------------------------------------------------
__global__ __launch_bounds__(256) void k_tab(const float* __restrict__ in,
                                             const __hip_bfloat16* __restrict__ BswH,
                                             const float* __restrict__ colbias,
                                             float* __restrict__ proj,
                                             __hip_bfloat16* __restrict__ tabs) {
    const short8* Bsw = reinterpret_cast<const short8*>(BswH);
    const int lane = threadIdx.x & 63;
    const int wv = threadIdx.x >> 6;
    const int r = lane & 15, q = lane >> 4;
    const int row0 = blockIdx.x * 16;

    short8 a[4];
    const float* ip = in + (size_t)(row0 + r) * IN_F + q * 8;
#pragma unroll
    for (int ks = 0; ks < 4; ++ks)
        a[ks] = pack8(*(const float4*)(ip + ks * 32), *(const float4*)(ip + ks * 32 + 4));

    for (int ctl = 0; ctl < 24; ++ctl) {
        const int ct = wv * 24 + ctl;
        const int c = ct * 16 + r;
        const float cb = colbias[c];
        f32x4 acc = {cb, cb, cb, cb};
#pragma unroll
        for (int ks = 0; ks < 4; ++ks)
            acc = __builtin_amdgcn_mfma_f32_16x16x32_bf16(a[ks], Bsw[(ct * 4 + ks) * 64 + lane], acc, 0, 0, 0);
        if (c < HF) {
#pragma unroll
            for (int i = 0; i < 4; ++i)
                proj[(size_t)(row0 + q * 4 + i) * HF + c] = acc[i];
        } else {
            const int t = (c - HF) >> 8;
            const int rem = (c - HF) & 255;
            __hip_bfloat16* tp = tabs + (size_t)t * TSZ;
#pragma unroll
            for (int i = 0; i < 4; ++i)
                tp[(size_t)(row0 + q * 4 + i) * HF + rem] = __float2bfloat16(acc[i]);
        }
    }
}

// ---------------------------------------------------------------------------
// K2: per-edge kernel, 16 edges per wave, MFMA second layer.
// lane: r = lane&15 (edge slot), q = lane>>4 (feature chunk).
// ---------------------------------------------------------------------------
__global__ __launch_bounds__(256) void k_edge(
        const int* __restrict__ eidx,
        const __hip_bfloat16* __restrict__ tabs,
        const float* __restrict__ attW2, const float* __restrict__ attb2,
        const float* __restrict__ eW2, const float* __restrict__ eb2,
        float* __restrict__ out, int nwaves) {
    const __hip_bfloat16* u1 = tabs;
    const __hip_bfloat16* u2 = tabs + TSZ;
    const __hip_bfloat16* u3 = tabs + 2 * TSZ;
    const __hip_bfloat16* v1t = tabs + 3 * TSZ;
    const __hip_bfloat16* v2t = tabs + 4 * TSZ;

    const int lane = threadIdx.x & 63;
    const int gw = (int)((blockIdx.x * blockDim.x + threadIdx.x) >> 6);
    const int r = lane & 15, q = lane >> 4;

    // e_W2 as B-frags: frag (ct,s): lane holds row ct*16+r, feats s*32+q*8..+7
    short8 bfr[4][2];
#pragma unroll
    for (int ct = 0; ct < 4; ++ct)
#pragma unroll
        for (int s2 = 0; s2 < 2; ++s2) {
            const float* wp = eW2 + (ct * 16 + r) * FD + s2 * 32 + q * 8;
            bfr[ct][s2] = pack8(*(const float4*)wp, *(const float4*)(wp + 4));
        }

    float awlo[8], awhi[8];
    {
        float4 w0 = *(const float4*)(attW2 + q * 8);
        float4 w1 = *(const float4*)(attW2 + q * 8 + 4);
        awlo[0] = w0.x; awlo[1] = w0.y; awlo[2] = w0.z; awlo[3] = w0.w;
        awlo[4] = w1.x; awlo[5] = w1.y; awlo[6] = w1.z; awlo[7] = w1.w;
        float4 w2 = *(const float4*)(attW2 + 32 + q * 8);
        float4 w3 = *(const float4*)(attW2 + 32 + q * 8 + 4);
        awhi[0] = w2.x; awhi[1] = w2.y; awhi[2] = w2.z; awhi[3] = w2.w;
        awhi[4] = w3.x; awhi[5] = w3.y; awhi[6] = w3.z; awhi[7] = w3.w;
    }
    float eb2v[4];
#pragma unroll
    for (int ct = 0; ct < 4; ++ct) eb2v[ct] = eb2[ct * 16 + r];
    const float ab2s = attb2[0];

    for (int tile = gw; tile < NTILES; tile += nwaves) {
        const int e0 = tile * 16;
        const int ni = eidx[e0 + r];
        const int nj = eidx[N_EDGES + e0 + r];
        const int nk = eidx[2 * N_EDGES + e0 + r];
        int ni4[4], nj4[4], nk4[4];
#pragma unroll
        for (int i = 0; i < 4; ++i) {
            ni4[i] = __shfl(ni, q * 4 + i);
            nj4[i] = __shfl(nj, q * 4 + i);
            nk4[i] = __shfl(nk, q * 4 + i);
        }

        // ---- attention scores (u1 already holds +ab1) ----
        float s[4];
#pragma unroll
        for (int h = 0; h < 4; ++h) {
            const size_t bi = (((size_t)ni * HEADS + h) << 6) + q * 8;
            const size_t bj = (((size_t)nj * HEADS + h) << 6) + q * 8;
            const size_t bk = (((size_t)nk * HEADS + h) << 6) + q * 8;
            uint4 a0 = *(const uint4*)(u1 + bi), a1 = *(const uint4*)(u1 + bi + 32);
            uint4 b0 = *(const uint4*)(u2 + bj), b1 = *(const uint4*)(u2 + bj + 32);
            uint4 c0 = *(const uint4*)(u3 + bk), c1 = *(const uint4*)(u3 + bk + 32);
            float p = score8(a0, b0, c0, awlo) + score8(a1, b1, c1, awhi);
            p += __shfl_xor(p, 16);
            p += __shfl_xor(p, 32);
            const float sc = p + ab2s;
            s[h] = fmaxf(sc, 0.2f * sc);
        }
        const float mx = fmaxf(fmaxf(s[0], s[1]), fmaxf(s[2], s[3]));
        const float x0 = __expf(s[0] - mx), x1 = __expf(s[1] - mx);
        const float x2 = __expf(s[2] - mx), x3 = __expf(s[3] - mx);
        const float rs = 1.f / (x0 + x1 + x2 + x3);
        float att[4] = {x0 * rs, x1 * rs, x2 * rs, x3 * rs};

        float* const outp = out;
#pragma unroll
        for (int h = 0; h < 4; ++h) {
            float at4[4];
#pragma unroll
            for (int i = 0; i < 4; ++i) at4[i] = __shfl(att[h], q * 4 + i);

            const size_t bi = (((size_t)ni * HEADS + h) << 6) + q * 8;
            const size_t bj = (((size_t)nj * HEADS + h) << 6) + q * 8;
            const size_t bk = (((size_t)nk * HEADS + h) << 6) + q * 8;
            // v1 table already holds +eb1
            uint4 v1i0 = *(const uint4*)(v1t + bi), v1i1 = *(const uint4*)(v1t + bi + 32);
            uint4 v1j0 = *(const uint4*)(v1t + bj), v1j1 = *(const uint4*)(v1t + bj + 32);
            uint4 v2j0 = *(const uint4*)(v2t + bj), v2j1 = *(const uint4*)(v2t + bj + 32);
            uint4 v2k0 = *(const uint4*)(v2t + bk), v2k1 = *(const uint4*)(v2t + bk + 32);

            auto emit = [&](short8 A0, short8 A1, const int* nd, int tt) {
#pragma unroll
                for (int ct = 0; ct < 4; ++ct) {
                    f32x4 acc = {eb2v[ct], eb2v[ct], eb2v[ct], eb2v[ct]};
                    acc = __builtin_amdgcn_mfma_f32_16x16x32_bf16(A0, bfr[ct][0], acc, 0, 0, 0);
                    acc = __builtin_amdgcn_mfma_f32_16x16x32_bf16(A1, bfr[ct][1], acc, 0, 0, 0);
                    float* ob = outp + (size_t)tt * N_NODES * HF + h * FD + ct * 16 + r;
#pragma unroll
                    for (int i = 0; i < 4; ++i)
                        atomicAdd(ob + (size_t)nd[i] * HF, at4[i] * acc[i]);
                }
            };
            emit(gpack(v1j0, v2k0), gpack(v1j1, v2k1), ni4, 0);   // (pj,pk) -> i
            emit(gpack(v1i0, v2k0), gpack(v1i1, v2k1), nj4, 1);   // (pi,pk) -> j
            emit(gpack(v1i0, v2j0), gpack(v1i1, v2j1), nk4, 2);   // (pi,pj) -> k
        }
    }
}

// ---------------------------------------------------------------------------
// K3: out = elu(theta*proj + segsum + bias), float4-vectorized
// ---------------------------------------------------------------------------
__global__ __launch_bounds__(256) void k_final(const float* __restrict__ proj,
                                               const float* __restrict__ theta,
                                               const float* __restrict__ bias,
                                               float* __restrict__ out) {
    const size_t i4 = (size_t)blockIdx.x * 256 + threadIdx.x;
    const size_t e = i4 * 4;
    const int hf = (int)(e & (HF - 1));
    const size_t row = e >> 8;
    const int n = (int)(row % N_NODES);
    float4 t4 = *(const float4*)(theta + hf);
    float4 b4 = *(const float4*)(bias + hf);
    float4 p4 = *(const float4*)(proj + (size_t)n * HF + hf);
    float4 o4 = *(const float4*)(out + e);
    float v;
    v = t4.x * p4.x + o4.x + b4.x; o4.x = v > 0.f ? v : expm1f(v);
    v = t4.y * p4.y + o4.y + b4.y; o4.y = v > 0.f ? v : expm1f(v);
    v = t4.z * p4.z + o4.z + b4.z; o4.z = v > 0.f ? v : expm1f(v);
    v = t4.w * p4.w + o4.w + b4.w; o4.w = v > 0.f ? v : expm1f(v);
    *(float4*)(out + e) = o4;
}

// ---------------------------------------------------------------------------
extern "C" void kernel_launch(void* const* d_in, const int* in_sizes, int n_in,
                              void* d_out, int out_size, void* d_ws, size_t ws_size,
                              hipStream_t stream) {
    const float* in_nodes = (const float*)d_in[0];
    const int*   eidx     = (const int*)d_in[1];
    const float* Wp       = (const float*)d_in[2];
    const float* attW1    = (const float*)d_in[3];
    const float* attb1    = (const float*)d_in[4];
    const float* attW2    = (const float*)d_in[5];
    const float* attb2    = (const float*)d_in[6];
    const float* eW1      = (const float*)d_in[7];
    const float* eb1      = (const float*)d_in[8];
    const float* eW2      = (const float*)d_in[9];
    const float* eb2      = (const float*)d_in[10];
    const float* theta    = (const float*)d_in[11];
    const float* bias     = (const float*)d_in[12];

    float* proj = (float*)d_ws;                                        // 51.2 MB
    __hip_bfloat16* tabs =
        (__hip_bfloat16*)((char*)d_ws + (size_t)N_NODES * HF * 4);     // 128 MB

    // Stash composed weights in the tail of d_out (erased by the memset below
    // AFTER k_tab has consumed them — stream-ordered, capture-safe).
    __hip_bfloat16* Bsw = (__hip_bfloat16*)((char*)d_out + 152000000);
    float* colbias = (float*)((char*)d_out + 152000000 + 393216);

    float* out = (float*)d_out;

    k_comp<<<NCOLS, 128, 0, stream>>>(Wp, attW1, eW1, attb1, eb1, Bsw, colbias);
    k_tab<<<N_NODES / 16, 256, 0, stream>>>(in_nodes, Bsw, colbias, proj, tabs);
    hipMemsetAsync(d_out, 0, (size_t)out_size * sizeof(float), stream);
    k_edge<<<NTILES / 4, 256, 0, stream>>>(eidx, tabs, attW2, attb2, eW2, eb2,
                                           out, NTILES);
    k_final<<<(3 * N_NODES * HF) / 1024, 256, 0, stream>>>(proj, theta, bias, out);
}

// Round 3
// 680.759 us; speedup vs baseline: 1.4565x; 1.0062x over previous
//
#include <hip/hip_runtime.h>
#include <hip/hip_bf16.h>

#define N_NODES 50000
#define N_EDGES 200000
#define IN_F 128
#define HEADS 4
#define FD 64
#define HF 256
#define NROWS (N_NODES * HEADS)
#define NCOLS 1536                 // 256 proj cols + 5*256 table cols
#define NTILES (N_EDGES / 16)      // 12500, exact
#define TROW 320                   // 5*64 bf16 elems per (node,head) row

typedef __attribute__((ext_vector_type(8))) short short8;
typedef __attribute__((ext_vector_type(4))) float f32x4;

__device__ inline short bf16_of(float x) {
    __hip_bfloat16 h = __float2bfloat16(x);
    return *reinterpret_cast<short*>(&h);
}
__device__ inline short8 pack8(float4 a, float4 b) {
    short8 o;
    o[0] = bf16_of(a.x); o[1] = bf16_of(a.y); o[2] = bf16_of(a.z); o[3] = bf16_of(a.w);
    o[4] = bf16_of(b.x); o[5] = bf16_of(b.y); o[6] = bf16_of(b.z); o[7] = bf16_of(b.w);
    return o;
}
__device__ inline void unpk(uint4 v, float* f) {
    f[0] = __uint_as_float(v.x << 16); f[1] = __uint_as_float(v.x & 0xffff0000u);
    f[2] = __uint_as_float(v.y << 16); f[3] = __uint_as_float(v.y & 0xffff0000u);
    f[4] = __uint_as_float(v.z << 16); f[5] = __uint_as_float(v.z & 0xffff0000u);
    f[6] = __uint_as_float(v.w << 16); f[7] = __uint_as_float(v.w & 0xffff0000u);
}
__device__ inline short8 gpack(uint4 ua, uint4 ub) {   // leakyrelu(a+b, 0.2) -> bf16x8
    float fa[8], fb[8]; unpk(ua, fa); unpk(ub, fb);
    short8 o;
#pragma unroll
    for (int j = 0; j < 8; ++j) {
        float x = fa[j] + fb[j];
        x = fmaxf(x, 0.2f * x);
        o[j] = bf16_of(x);
    }
    return o;
}
__device__ inline float score8(uint4 ua, uint4 ub, uint4 uc, const float* w) {
    float fa[8], fb[8], fc[8]; unpk(ua, fa); unpk(ub, fb); unpk(uc, fc);
    float p = 0.f;
#pragma unroll
    for (int j = 0; j < 8; ++j) {
        float x = fa[j] + fb[j] + fc[j];
        x = fmaxf(x, 0.f);
        p = fmaf(x, w[j], p);
    }
    return p;
}

// ---------------------------------------------------------------------------
// K0: compose weights (W_comp = table_W1 · W_proj_head), pre-swizzled B-frags.
// ---------------------------------------------------------------------------
__global__ __launch_bounds__(128) void k_comp(const float* __restrict__ Wp,
                                              const float* __restrict__ attW1,
                                              const float* __restrict__ eW1,
                                              const float* __restrict__ attb1,
                                              const float* __restrict__ eb1,
                                              __hip_bfloat16* __restrict__ Bsw,
                                              float* __restrict__ colbias) {
    const int c = blockIdx.x;
    const int k = threadIdx.x;
    float acc;
    float cb = 0.f;
    if (c < HF) {
        acc = Wp[c * IN_F + k];
    } else {
        const int t = (c - HF) >> 8;
        const int rem = (c - HF) & 255;
        const int h = rem >> 6, g = rem & 63;
        const float* T;
        if (t == 0)      T = attW1 + g * 192;
        else if (t == 1) T = attW1 + g * 192 + 64;
        else if (t == 2) T = attW1 + g * 192 + 128;
        else if (t == 3) T = eW1 + g * 128;
        else             T = eW1 + g * 128 + 64;
        acc = 0.f;
        for (int f = 0; f < 64; ++f)
            acc += T[f] * Wp[(h * 64 + f) * IN_F + k];
        if (t == 0) cb = attb1[g];
        else if (t == 3) cb = eb1[g];
    }
    const int ct = c >> 4, cin = c & 15, ks = k >> 5, kin = k & 31, j = k & 7;
    const int l = cin + ((kin >> 3) << 4);
    Bsw[((ct * 4 + ks) * 64 + l) * 8 + j] = __float2bfloat16(acc);
    if (k == 0) colbias[c] = cb;
}

// ---------------------------------------------------------------------------
// K1: [50000 x 128] @ [128 x 1536] MFMA GEMM -> proj (f32) + packed bf16 tables
// tabs layout: ((node*4 + h)*5 + t)*64 + g
// ---------------------------------------------------------------------------
__global__ __launch_bounds__(256) void k_tab(const float* __restrict__ in,
                                             const __hip_bfloat16* __restrict__ BswH,
                                             const float* __restrict__ colbias,
                                             float* __restrict__ proj,
                                             __hip_bfloat16* __restrict__ tabs) {
    const short8* Bsw = reinterpret_cast<const short8*>(BswH);
    const int lane = threadIdx.x & 63;
    const int wv = threadIdx.x >> 6;
    const int r = lane & 15, q = lane >> 4;
    const int row0 = blockIdx.x * 16;

    short8 a[4];
    const float* ip = in + (size_t)(row0 + r) * IN_F + q * 8;
#pragma unroll
    for (int ks = 0; ks < 4; ++ks)
        a[ks] = pack8(*(const float4*)(ip + ks * 32), *(const float4*)(ip + ks * 32 + 4));

    for (int ctl = 0; ctl < 24; ++ctl) {
        const int ct = wv * 24 + ctl;
        const int c = ct * 16 + r;
        const float cb = colbias[c];
        f32x4 acc = {cb, cb, cb, cb};
#pragma unroll
        for (int ks = 0; ks < 4; ++ks)
            acc = __builtin_amdgcn_mfma_f32_16x16x32_bf16(a[ks], Bsw[(ct * 4 + ks) * 64 + lane], acc, 0, 0, 0);
        if (c < HF) {
#pragma unroll
            for (int i = 0; i < 4; ++i)
                proj[(size_t)(row0 + q * 4 + i) * HF + c] = acc[i];
        } else {
            const int t = (c - HF) >> 8;
            const int rem = (c - HF) & 255;
            const int h = rem >> 6, g = rem & 63;
#pragma unroll
            for (int i = 0; i < 4; ++i)
                tabs[(((size_t)(row0 + q * 4 + i) * HEADS + h) * 5 + t) * 64 + g] =
                    __float2bfloat16(acc[i]);
        }
    }
}

// ---------------------------------------------------------------------------
// K2: per-edge kernel. Block = 1 tile (16 edges) x 4 waves; wave = head.
// All 10 gathers of a (tile,head) issued up-front; softmax via LDS exchange.
// ---------------------------------------------------------------------------
__global__ __launch_bounds__(256) void k_edge(
        const int* __restrict__ eidx,
        const __hip_bfloat16* __restrict__ tabs,
        const float* __restrict__ attW2, const float* __restrict__ attb2,
        const float* __restrict__ eW2, const float* __restrict__ eb2,
        float* __restrict__ out) {
    __shared__ float s_lds[HEADS][16];
    __shared__ float att_lds[HEADS][16];

    const int lane = threadIdx.x & 63;
    const int h = threadIdx.x >> 6;            // wave index == head
    const int r = lane & 15, q = lane >> 4;
    const int e0 = blockIdx.x * 16;

    // e_W2 B-frags (L2-hot after first blocks)
    short8 bfr[4][2];
#pragma unroll
    for (int ct = 0; ct < 4; ++ct)
#pragma unroll
        for (int s2 = 0; s2 < 2; ++s2) {
            const float* wp = eW2 + (ct * 16 + r) * FD + s2 * 32 + q * 8;
            bfr[ct][s2] = pack8(*(const float4*)wp, *(const float4*)(wp + 4));
        }
    float awlo[8], awhi[8];
    {
        float4 w0 = *(const float4*)(attW2 + q * 8);
        float4 w1 = *(const float4*)(attW2 + q * 8 + 4);
        awlo[0] = w0.x; awlo[1] = w0.y; awlo[2] = w0.z; awlo[3] = w0.w;
        awlo[4] = w1.x; awlo[5] = w1.y; awlo[6] = w1.z; awlo[7] = w1.w;
        float4 w2 = *(const float4*)(attW2 + 32 + q * 8);
        float4 w3 = *(const float4*)(attW2 + 32 + q * 8 + 4);
        awhi[0] = w2.x; awhi[1] = w2.y; awhi[2] = w2.z; awhi[3] = w2.w;
        awhi[4] = w3.x; awhi[5] = w3.y; awhi[6] = w3.z; awhi[7] = w3.w;
    }
    float eb2v[4];
#pragma unroll
    for (int ct = 0; ct < 4; ++ct) eb2v[ct] = eb2[ct * 16 + r];
    const float ab2s = attb2[0];

    const int ni = eidx[e0 + r];
    const int nj = eidx[N_EDGES + e0 + r];
    const int nk = eidx[2 * N_EDGES + e0 + r];

    const size_t bi = ((size_t)ni * HEADS + h) * TROW + q * 8;
    const size_t bj = ((size_t)nj * HEADS + h) * TROW + q * 8;
    const size_t bk = ((size_t)nk * HEADS + h) * TROW + q * 8;

    // ---- issue ALL gathers (independent) ----
    uint4 a0 = *(const uint4*)(tabs + bi);            // u1
    uint4 a1 = *(const uint4*)(tabs + bi + 32);
    uint4 b0 = *(const uint4*)(tabs + bj + 64);       // u2
    uint4 b1 = *(const uint4*)(tabs + bj + 96);
    uint4 c0 = *(const uint4*)(tabs + bk + 128);      // u3
    uint4 c1 = *(const uint4*)(tabs + bk + 160);
    uint4 v1i0 = *(const uint4*)(tabs + bi + 192);    // v1(ni)  (+eb1 folded)
    uint4 v1i1 = *(const uint4*)(tabs + bi + 224);
    uint4 v1j0 = *(const uint4*)(tabs + bj + 192);    // v1(nj)
    uint4 v1j1 = *(const uint4*)(tabs + bj + 224);
    uint4 v2j0 = *(const uint4*)(tabs + bj + 256);    // v2(nj)
    uint4 v2j1 = *(const uint4*)(tabs + bj + 288);
    uint4 v2k0 = *(const uint4*)(tabs + bk + 256);    // v2(nk)
    uint4 v2k1 = *(const uint4*)(tabs + bk + 288);

    // ---- score for this head ----
    float p = score8(a0, b0, c0, awlo) + score8(a1, b1, c1, awhi);
    p += __shfl_xor(p, 16);
    p += __shfl_xor(p, 32);
    float sc = p + ab2s;
    sc = fmaxf(sc, 0.2f * sc);
    if (lane < 16) s_lds[h][lane] = sc;
    __syncthreads();

    if (lane < 16) {
        const float s0 = s_lds[0][lane], s1 = s_lds[1][lane];
        const float s2 = s_lds[2][lane], s3 = s_lds[3][lane];
        const float mx = fmaxf(fmaxf(s0, s1), fmaxf(s2, s3));
        const float x0 = __expf(s0 - mx), x1 = __expf(s1 - mx);
        const float x2 = __expf(s2 - mx), x3 = __expf(s3 - mx);
        const float rs = 1.f / (x0 + x1 + x2 + x3);
        const float xh = (h == 0) ? x0 : (h == 1) ? x1 : (h == 2) ? x2 : x3;
        att_lds[h][lane] = xh * rs;
    }
    __syncthreads();

    float at4[4];
#pragma unroll
    for (int i = 0; i < 4; ++i) at4[i] = att_lds[h][q * 4 + i];
    int ni4[4], nj4[4], nk4[4];
#pragma unroll
    for (int i = 0; i < 4; ++i) {
        ni4[i] = __shfl(ni, q * 4 + i);
        nj4[i] = __shfl(nj, q * 4 + i);
        nk4[i] = __shfl(nk, q * 4 + i);
    }

    auto emit = [&](short8 A0, short8 A1, const int* nd, int tt) {
#pragma unroll
        for (int ct = 0; ct < 4; ++ct) {
            f32x4 acc = {eb2v[ct], eb2v[ct], eb2v[ct], eb2v[ct]};
            acc = __builtin_amdgcn_mfma_f32_16x16x32_bf16(A0, bfr[ct][0], acc, 0, 0, 0);
            acc = __builtin_amdgcn_mfma_f32_16x16x32_bf16(A1, bfr[ct][1], acc, 0, 0, 0);
            float* ob = out + (size_t)tt * N_NODES * HF + h * FD + ct * 16 + r;
#pragma unroll
            for (int i = 0; i < 4; ++i)
                atomicAdd(ob + (size_t)nd[i] * HF, at4[i] * acc[i]);
        }
    };
    emit(gpack(v1j0, v2k0), gpack(v1j1, v2k1), ni4, 0);   // (pj,pk) -> i
    emit(gpack(v1i0, v2k0), gpack(v1i1, v2k1), nj4, 1);   // (pi,pk) -> j
    emit(gpack(v1i0, v2j0), gpack(v1i1, v2j1), nk4, 2);   // (pi,pj) -> k
}

// ---------------------------------------------------------------------------
// K3: out = elu(theta*proj + segsum + bias), float4-vectorized
// ---------------------------------------------------------------------------
__global__ __launch_bounds__(256) void k_final(const float* __restrict__ proj,
                                               const float* __restrict__ theta,
                                               const float* __restrict__ bias,
                                               float* __restrict__ out) {
    const size_t i4 = (size_t)blockIdx.x * 256 + threadIdx.x;
    const size_t e = i4 * 4;
    const int hf = (int)(e & (HF - 1));
    const size_t row = e >> 8;
    const int n = (int)(row % N_NODES);
    float4 t4 = *(const float4*)(theta + hf);
    float4 b4 = *(const float4*)(bias + hf);
    float4 p4 = *(const float4*)(proj + (size_t)n * HF + hf);
    float4 o4 = *(const float4*)(out + e);
    float v;
    v = t4.x * p4.x + o4.x + b4.x; o4.x = v > 0.f ? v : expm1f(v);
    v = t4.y * p4.y + o4.y + b4.y; o4.y = v > 0.f ? v : expm1f(v);
    v = t4.z * p4.z + o4.z + b4.z; o4.z = v > 0.f ? v : expm1f(v);
    v = t4.w * p4.w + o4.w + b4.w; o4.w = v > 0.f ? v : expm1f(v);
    *(float4*)(out + e) = o4;
}

// ---------------------------------------------------------------------------
extern "C" void kernel_launch(void* const* d_in, const int* in_sizes, int n_in,
                              void* d_out, int out_size, void* d_ws, size_t ws_size,
                              hipStream_t stream) {
    const float* in_nodes = (const float*)d_in[0];
    const int*   eidx     = (const int*)d_in[1];
    const float* Wp       = (const float*)d_in[2];
    const float* attW1    = (const float*)d_in[3];
    const float* attb1    = (const float*)d_in[4];
    const float* attW2    = (const float*)d_in[5];
    const float* attb2    = (const float*)d_in[6];
    const float* eW1      = (const float*)d_in[7];
    const float* eb1      = (const float*)d_in[8];
    const float* eW2      = (const float*)d_in[9];
    const float* eb2      = (const float*)d_in[10];
    const float* theta    = (const float*)d_in[11];
    const float* bias     = (const float*)d_in[12];

    float* proj = (float*)d_ws;                                        // 51.2 MB
    __hip_bfloat16* tabs =
        (__hip_bfloat16*)((char*)d_ws + (size_t)N_NODES * HF * 4);     // 128 MB

    // Stash composed weights in the tail of d_out (consumed by k_tab, then
    // erased by the stream-ordered memset below — capture-safe).
    __hip_bfloat16* Bsw = (__hip_bfloat16*)((char*)d_out + 152000000);
    float* colbias = (float*)((char*)d_out + 152000000 + 393216);

    float* out = (float*)d_out;

    k_comp<<<NCOLS, 128, 0, stream>>>(Wp, attW1, eW1, attb1, eb1, Bsw, colbias);
    k_tab<<<N_NODES / 16, 256, 0, stream>>>(in_nodes, Bsw, colbias, proj, tabs);
    hipMemsetAsync(d_out, 0, (size_t)out_size * sizeof(float), stream);
    k_edge<<<NTILES, 256, 0, stream>>>(eidx, tabs, attW2, attb2, eW2, eb2, out);
    k_final<<<(3 * N_NODES * HF) / 1024, 256, 0, stream>>>(proj, theta, bias, out);
}

// Round 4
// 465.198 us; speedup vs baseline: 2.1314x; 1.4634x over previous
//
#include <hip/hip_runtime.h>
#include <hip/hip_bf16.h>

#define N_NODES 50000
#define N_EDGES 200000
#define IN_F 128
#define HEADS 4
#define FD 64
#define HF 256
#define NCOLS 1536
#define NT3 (3 * N_NODES)          // 150000 segment rows (t-major)
#define E3  (3 * N_EDGES)          // 600000 slots
#define TROW 320                   // 5*64 bf16 per (node,head)

// ---- ws byte offsets (total ~268 MB) ----
#define OFF_PROJ   0UL
#define OFF_TABS   51200000UL
#define OFF_SBUF   179200000UL
#define OFF_ATT    256000000UL
#define OFF_ALPHA  259200000UL
#define OFF_RANK   261600000UL
#define OFF_ELIST  264000000UL
#define OFF_CNT    266400000UL
#define OFF_OFFS   267000000UL
#define OFF_BSUM   267600008UL
#define OFF_BSW    267601040UL
#define OFF_CB     267994256UL

typedef __attribute__((ext_vector_type(8))) short short8;
typedef __attribute__((ext_vector_type(4))) float f32x4;

__device__ inline short bf16_of(float x) {
    __hip_bfloat16 h = __float2bfloat16(x);
    return *reinterpret_cast<short*>(&h);
}
__device__ inline unsigned pack2(float lo, float hi) {
    return ((unsigned)(unsigned short)bf16_of(hi) << 16) |
           (unsigned)(unsigned short)bf16_of(lo);
}
__device__ inline short8 pack8(float4 a, float4 b) {
    short8 o;
    o[0] = bf16_of(a.x); o[1] = bf16_of(a.y); o[2] = bf16_of(a.z); o[3] = bf16_of(a.w);
    o[4] = bf16_of(b.x); o[5] = bf16_of(b.y); o[6] = bf16_of(b.z); o[7] = bf16_of(b.w);
    return o;
}
__device__ inline void unpk(uint4 v, float* f) {
    f[0] = __uint_as_float(v.x << 16); f[1] = __uint_as_float(v.x & 0xffff0000u);
    f[2] = __uint_as_float(v.y << 16); f[3] = __uint_as_float(v.y & 0xffff0000u);
    f[4] = __uint_as_float(v.z << 16); f[5] = __uint_as_float(v.z & 0xffff0000u);
    f[6] = __uint_as_float(v.w << 16); f[7] = __uint_as_float(v.w & 0xffff0000u);
}
__device__ inline float score8(uint4 ua, uint4 ub, uint4 uc, const float* w) {
    float fa[8], fb[8], fc[8]; unpk(ua, fa); unpk(ub, fb); unpk(uc, fc);
    float p = 0.f;
#pragma unroll
    for (int j = 0; j < 8; ++j) {
        float x = fa[j] + fb[j] + fc[j];
        x = fmaxf(x, 0.f);
        p = fmaf(x, w[j], p);
    }
    return p;
}

// ---------------------------------------------------------------------------
// K0: compose weights (table_W1 · W_proj_head) -> pre-swizzled B-frags + colbias
// ---------------------------------------------------------------------------
__global__ __launch_bounds__(128) void k_comp(const float* __restrict__ Wp,
                                              const float* __restrict__ attW1,
                                              const float* __restrict__ eW1,
                                              const float* __restrict__ attb1,
                                              const float* __restrict__ eb1,
                                              __hip_bfloat16* __restrict__ Bsw,
                                              float* __restrict__ colbias) {
    const int c = blockIdx.x;
    const int k = threadIdx.x;
    float acc;
    float cb = 0.f;
    if (c < HF) {
        acc = Wp[c * IN_F + k];
    } else {
        const int t = (c - HF) >> 8;
        const int rem = (c - HF) & 255;
        const int h = rem >> 6, g = rem & 63;
        const float* T;
        if (t == 0)      T = attW1 + g * 192;
        else if (t == 1) T = attW1 + g * 192 + 64;
        else if (t == 2) T = attW1 + g * 192 + 128;
        else if (t == 3) T = eW1 + g * 128;
        else             T = eW1 + g * 128 + 64;
        acc = 0.f;
        for (int f = 0; f < 64; ++f)
            acc += T[f] * Wp[(h * 64 + f) * IN_F + k];
        if (t == 0) cb = attb1[g];
        else if (t == 3) cb = eb1[g];
    }
    const int ct = c >> 4, cin = c & 15, kin = k & 31, j = k & 7;
    const int ks = k >> 5;
    const int l = cin + ((kin >> 3) << 4);
    Bsw[((ct * 4 + ks) * 64 + l) * 8 + j] = __float2bfloat16(acc);
    if (k == 0) colbias[c] = cb;
}

// ---------------------------------------------------------------------------
// K1: [50000x128] @ [128x1536] MFMA GEMM -> proj f32 + packed bf16 tables
// tabs layout: ((node*4 + h)*5 + t)*64 + g
// ---------------------------------------------------------------------------
__global__ __launch_bounds__(256) void k_tab(const float* __restrict__ in,
                                             const __hip_bfloat16* __restrict__ BswH,
                                             const float* __restrict__ colbias,
                                             float* __restrict__ proj,
                                             __hip_bfloat16* __restrict__ tabs) {
    const short8* Bsw = reinterpret_cast<const short8*>(BswH);
    const int lane = threadIdx.x & 63;
    const int wv = threadIdx.x >> 6;
    const int r = lane & 15, q = lane >> 4;
    const int row0 = blockIdx.x * 16;

    short8 a[4];
    const float* ip = in + (size_t)(row0 + r) * IN_F + q * 8;
#pragma unroll
    for (int ks = 0; ks < 4; ++ks)
        a[ks] = pack8(*(const float4*)(ip + ks * 32), *(const float4*)(ip + ks * 32 + 4));

    for (int ctl = 0; ctl < 24; ++ctl) {
        const int ct = wv * 24 + ctl;
        const int c = ct * 16 + r;
        const float cb = colbias[c];
        f32x4 acc = {cb, cb, cb, cb};
#pragma unroll
        for (int ks = 0; ks < 4; ++ks)
            acc = __builtin_amdgcn_mfma_f32_16x16x32_bf16(a[ks], Bsw[(ct * 4 + ks) * 64 + lane], acc, 0, 0, 0);
        if (c < HF) {
#pragma unroll
            for (int i = 0; i < 4; ++i)
                proj[(size_t)(row0 + q * 4 + i) * HF + c] = acc[i];
        } else {
            const int t = (c - HF) >> 8;
            const int rem = (c - HF) & 255;
            const int h = rem >> 6, g = rem & 63;
#pragma unroll
            for (int i = 0; i < 4; ++i)
                tabs[(((size_t)(row0 + q * 4 + i) * HEADS + h) * 5 + t) * 64 + g] =
                    __float2bfloat16(acc[i]);
        }
    }
}

// ---------------------------------------------------------------------------
// Sort chain: hist -> scan (3 kernels) -> scatter edge ids
// ---------------------------------------------------------------------------
__global__ __launch_bounds__(256) void k_hist(const int* __restrict__ eidx,
                                              int* __restrict__ cnt,
                                              int* __restrict__ rank) {
    const int g = blockIdx.x * 256 + threadIdx.x;
    if (g < E3) {
        const int node = eidx[g];
        const int t = g / N_EDGES;
        rank[g] = atomicAdd(&cnt[t * N_NODES + node], 1);
    }
}

__global__ __launch_bounds__(256) void k_scan1(const int* __restrict__ cnt,
                                               int* __restrict__ offs,
                                               int* __restrict__ bsums) {
    __shared__ int lds[256];
    const int b = blockIdx.x, t = threadIdx.x;
    const int base = b * 1024 + t * 4;
    int v[4];
#pragma unroll
    for (int c = 0; c < 4; ++c) v[c] = (base + c < NT3) ? cnt[base + c] : 0;
    const int s = v[0] + v[1] + v[2] + v[3];
    lds[t] = s;
    __syncthreads();
    for (int off = 1; off < 256; off <<= 1) {
        int x = (t >= off) ? lds[t - off] : 0;
        __syncthreads();
        lds[t] += x;
        __syncthreads();
    }
    if (t == 255) bsums[b] = lds[255];
    int run = lds[t] - s;
#pragma unroll
    for (int c = 0; c < 4; ++c) {
        if (base + c < NT3) offs[base + c] = run;
        run += v[c];
    }
}

__global__ __launch_bounds__(256) void k_scan2(int* __restrict__ bsums, int nb) {
    __shared__ int lds[256];
    const int t = threadIdx.x;
    const int v = (t < nb) ? bsums[t] : 0;
    lds[t] = v;
    __syncthreads();
    for (int off = 1; off < 256; off <<= 1) {
        int x = (t >= off) ? lds[t - off] : 0;
        __syncthreads();
        lds[t] += x;
        __syncthreads();
    }
    if (t < nb) bsums[t] = lds[t] - v;
}

__global__ __launch_bounds__(256) void k_scan3(int* __restrict__ offs,
                                               const int* __restrict__ bsums) {
    const int i = blockIdx.x * 256 + threadIdx.x;
    if (i < NT3) offs[i] += bsums[i >> 10];
    if (i == NT3) offs[NT3] = E3;
}

__global__ __launch_bounds__(256) void k_scat(const int* __restrict__ eidx,
                                              const int* __restrict__ offs,
                                              const int* __restrict__ rank,
                                              int* __restrict__ elist) {
    const int g = blockIdx.x * 256 + threadIdx.x;
    if (g < E3) {
        const int node = eidx[g];
        const int t = g / N_EDGES;
        const int e = g - t * N_EDGES;
        elist[offs[t * N_NODES + node] + rank[g]] = e;
    }
}

// ---------------------------------------------------------------------------
// K2: attention scores -> attbuf[e][4]. Block = 16 edges x 4 waves (wave=head).
// ---------------------------------------------------------------------------
__global__ __launch_bounds__(256) void k_att(
        const int* __restrict__ eidx,
        const __hip_bfloat16* __restrict__ tabs,
        const float* __restrict__ attW2, const float* __restrict__ attb2,
        float* __restrict__ attbuf) {
    __shared__ float s_lds[HEADS][16];
    const int lane = threadIdx.x & 63;
    const int h = threadIdx.x >> 6;
    const int r = lane & 15, q = lane >> 4;
    const int e0 = blockIdx.x * 16;

    float awlo[8], awhi[8];
    {
        float4 w0 = *(const float4*)(attW2 + q * 8);
        float4 w1 = *(const float4*)(attW2 + q * 8 + 4);
        awlo[0] = w0.x; awlo[1] = w0.y; awlo[2] = w0.z; awlo[3] = w0.w;
        awlo[4] = w1.x; awlo[5] = w1.y; awlo[6] = w1.z; awlo[7] = w1.w;
        float4 w2 = *(const float4*)(attW2 + 32 + q * 8);
        float4 w3 = *(const float4*)(attW2 + 32 + q * 8 + 4);
        awhi[0] = w2.x; awhi[1] = w2.y; awhi[2] = w2.z; awhi[3] = w2.w;
        awhi[4] = w3.x; awhi[5] = w3.y; awhi[6] = w3.z; awhi[7] = w3.w;
    }
    const float ab2s = attb2[0];

    const int ni = eidx[e0 + r];
    const int nj = eidx[N_EDGES + e0 + r];
    const int nk = eidx[2 * N_EDGES + e0 + r];

    const size_t bi = ((size_t)ni * HEADS + h) * TROW + q * 8;
    const size_t bj = ((size_t)nj * HEADS + h) * TROW + q * 8;
    const size_t bk = ((size_t)nk * HEADS + h) * TROW + q * 8;

    uint4 a0 = *(const uint4*)(tabs + bi);
    uint4 a1 = *(const uint4*)(tabs + bi + 32);
    uint4 b0 = *(const uint4*)(tabs + bj + 64);
    uint4 b1 = *(const uint4*)(tabs + bj + 96);
    uint4 c0 = *(const uint4*)(tabs + bk + 128);
    uint4 c1 = *(const uint4*)(tabs + bk + 160);

    float p = score8(a0, b0, c0, awlo) + score8(a1, b1, c1, awhi);
    p += __shfl_xor(p, 16);
    p += __shfl_xor(p, 32);
    float sc = p + ab2s;
    sc = fmaxf(sc, 0.2f * sc);
    if (lane < 16) s_lds[h][lane] = sc;
    __syncthreads();
    if (lane < 16) {
        const float s0 = s_lds[0][lane], s1 = s_lds[1][lane];
        const float s2 = s_lds[2][lane], s3 = s_lds[3][lane];
        const float mx = fmaxf(fmaxf(s0, s1), fmaxf(s2, s3));
        const float x0 = __expf(s0 - mx), x1 = __expf(s1 - mx);
        const float x2 = __expf(s2 - mx), x3 = __expf(s3 - mx);
        const float rs = 1.f / (x0 + x1 + x2 + x3);
        const float xh = (h == 0) ? x0 : (h == 1) ? x1 : (h == 2) ? x2 : x3;
        attbuf[(size_t)(e0 + lane) * 4 + h] = xh * rs;
    }
}

// ---------------------------------------------------------------------------
// K3: segment-sum via sorted gather. Wave per (t,node); lane = (h, r).
// S[h][4r..4r+3] = sum_e att * lrelu(v1[x]+v2[y]); alpha = sum att.
// ---------------------------------------------------------------------------
__global__ __launch_bounds__(256) void k_seg(const int* __restrict__ eidx,
                                             const int* __restrict__ offs,
                                             const int* __restrict__ elist,
                                             const float* __restrict__ attbuf,
                                             const __hip_bfloat16* __restrict__ tabs,
                                             __hip_bfloat16* __restrict__ sbuf,
                                             float* __restrict__ alphabuf) {
    const int lane = threadIdx.x & 63;
    const int w = threadIdx.x >> 6;
    const int h = lane >> 4, r = lane & 15;
    const int t = blockIdx.y;
    const int n = blockIdx.x * 4 + w;
    const int idx = t * N_NODES + n;
    const int p0 = offs[idx], p1 = offs[idx + 1];
    int s0, s1;
    if (t == 0)      { s0 = 1; s1 = 2; }
    else if (t == 1) { s0 = 0; s1 = 2; }
    else             { s0 = 0; s1 = 1; }

    float acc0 = 0.f, acc1 = 0.f, acc2 = 0.f, acc3 = 0.f, alpha = 0.f;
    for (int p = p0; p < p1; ++p) {
        const int e = elist[p];
        const int x = eidx[s0 * N_EDGES + e];
        const int y = eidx[s1 * N_EDGES + e];
        const float at = attbuf[(size_t)e * 4 + h];
        const __hip_bfloat16* v1p = tabs + (((size_t)x * 4 + h) * 5 + 3) * 64;
        const __hip_bfloat16* v2p = tabs + (((size_t)y * 4 + h) * 5 + 4) * 64;
        const uint2 ua = *(const uint2*)(v1p + r * 4);
        const uint2 ub = *(const uint2*)(v2p + r * 4);
        float g0 = __uint_as_float(ua.x << 16) + __uint_as_float(ub.x << 16);
        float g1 = __uint_as_float(ua.x & 0xffff0000u) + __uint_as_float(ub.x & 0xffff0000u);
        float g2 = __uint_as_float(ua.y << 16) + __uint_as_float(ub.y << 16);
        float g3 = __uint_as_float(ua.y & 0xffff0000u) + __uint_as_float(ub.y & 0xffff0000u);
        g0 = fmaxf(g0, 0.2f * g0); g1 = fmaxf(g1, 0.2f * g1);
        g2 = fmaxf(g2, 0.2f * g2); g3 = fmaxf(g3, 0.2f * g3);
        acc0 = fmaf(at, g0, acc0); acc1 = fmaf(at, g1, acc1);
        acc2 = fmaf(at, g2, acc2); acc3 = fmaf(at, g3, acc3);
        alpha += at;
    }
    const int rho = idx * 4 + h;
    uint2 st;
    st.x = pack2(acc0, acc1);
    st.y = pack2(acc2, acc3);
    *(uint2*)(sbuf + (size_t)rho * 64 + r * 4) = st;
    if (r == 0) alphabuf[rho] = alpha;
}

// ---------------------------------------------------------------------------
// K4: out[rho*64+f] = elu(theta*proj + (W2 S)[f] + alpha*b2[f] + bias)
// Tile = 16 rows x 64 cols, wave-level MFMA; 4 waves/block.
// ---------------------------------------------------------------------------
__global__ __launch_bounds__(256) void k_out(const __hip_bfloat16* __restrict__ sbuf,
                                             const float* __restrict__ alphabuf,
                                             const float* __restrict__ proj,
                                             const float* __restrict__ eW2,
                                             const float* __restrict__ eb2,
                                             const float* __restrict__ theta,
                                             const float* __restrict__ bias,
                                             float* __restrict__ out) {
    const int lane = threadIdx.x & 63;
    const int w = threadIdx.x >> 6;
    const int r = lane & 15, q = lane >> 4;
    const int t = blockIdx.y;
    const int tile = blockIdx.x * 4 + w;               // [0, 12500)
    const int rho0 = t * (4 * N_NODES) + tile * 16;

    short8 bfr[4][2];
#pragma unroll
    for (int ct = 0; ct < 4; ++ct)
#pragma unroll
        for (int s2 = 0; s2 < 2; ++s2) {
            const float* wp = eW2 + (ct * 16 + r) * FD + s2 * 32 + q * 8;
            bfr[ct][s2] = pack8(*(const float4*)wp, *(const float4*)(wp + 4));
        }

    const short8* s8 = reinterpret_cast<const short8*>(sbuf);
    const short8 A0 = s8[(size_t)(rho0 + r) * 8 + q];
    const short8 A1 = s8[(size_t)(rho0 + r) * 8 + 4 + q];

    float al[4];
#pragma unroll
    for (int i = 0; i < 4; ++i) al[i] = alphabuf[rho0 + q * 4 + i];

#pragma unroll
    for (int ct = 0; ct < 4; ++ct) {
        f32x4 acc = {0.f, 0.f, 0.f, 0.f};
        acc = __builtin_amdgcn_mfma_f32_16x16x32_bf16(A0, bfr[ct][0], acc, 0, 0, 0);
        acc = __builtin_amdgcn_mfma_f32_16x16x32_bf16(A1, bfr[ct][1], acc, 0, 0, 0);
        const int f = ct * 16 + r;
        const float b2f = eb2[f];
#pragma unroll
        for (int i = 0; i < 4; ++i) {
            const int rho = rho0 + q * 4 + i;
            const int hh = rho & 3;
            const int n = (rho >> 2) - t * N_NODES;
            const float pj = proj[(size_t)n * HF + hh * 64 + f];
            float val = theta[hh * 64 + f] * pj + acc[i] + al[i] * b2f + bias[hh * 64 + f];
            out[(size_t)rho * 64 + f] = val > 0.f ? val : expm1f(val);
        }
    }
}

// ---------------------------------------------------------------------------
extern "C" void kernel_launch(void* const* d_in, const int* in_sizes, int n_in,
                              void* d_out, int out_size, void* d_ws, size_t ws_size,
                              hipStream_t stream) {
    const float* in_nodes = (const float*)d_in[0];
    const int*   eidx     = (const int*)d_in[1];
    const float* Wp       = (const float*)d_in[2];
    const float* attW1    = (const float*)d_in[3];
    const float* attb1    = (const float*)d_in[4];
    const float* attW2    = (const float*)d_in[5];
    const float* attb2    = (const float*)d_in[6];
    const float* eW1      = (const float*)d_in[7];
    const float* eb1      = (const float*)d_in[8];
    const float* eW2      = (const float*)d_in[9];
    const float* eb2      = (const float*)d_in[10];
    const float* theta    = (const float*)d_in[11];
    const float* bias     = (const float*)d_in[12];

    char* ws = (char*)d_ws;
    float*          proj     = (float*)(ws + OFF_PROJ);
    __hip_bfloat16* tabs     = (__hip_bfloat16*)(ws + OFF_TABS);
    __hip_bfloat16* sbuf     = (__hip_bfloat16*)(ws + OFF_SBUF);
    float*          attbuf   = (float*)(ws + OFF_ATT);
    float*          alphabuf = (float*)(ws + OFF_ALPHA);
    int*            rank     = (int*)(ws + OFF_RANK);
    int*            elist    = (int*)(ws + OFF_ELIST);
    int*            cnt      = (int*)(ws + OFF_CNT);
    int*            offs     = (int*)(ws + OFF_OFFS);
    int*            bsums    = (int*)(ws + OFF_BSUM);
    __hip_bfloat16* Bsw      = (__hip_bfloat16*)(ws + OFF_BSW);
    float*          colbias  = (float*)(ws + OFF_CB);

    float* out = (float*)d_out;

    hipMemsetAsync(cnt, 0, NT3 * sizeof(int), stream);

    k_comp<<<NCOLS, 128, 0, stream>>>(Wp, attW1, eW1, attb1, eb1, Bsw, colbias);
    k_tab<<<N_NODES / 16, 256, 0, stream>>>(in_nodes, Bsw, colbias, proj, tabs);

    k_hist<<<(E3 + 255) / 256, 256, 0, stream>>>(eidx, cnt, rank);
    k_scan1<<<(NT3 + 1023) / 1024, 256, 0, stream>>>(cnt, offs, bsums);
    k_scan2<<<1, 256, 0, stream>>>(bsums, (NT3 + 1023) / 1024);
    k_scan3<<<(NT3 + 256) / 256, 256, 0, stream>>>(offs, bsums);
    k_scat<<<(E3 + 255) / 256, 256, 0, stream>>>(eidx, offs, rank, elist);

    k_att<<<N_EDGES / 16, 256, 0, stream>>>(eidx, tabs, attW2, attb2, attbuf);
    k_seg<<<dim3(N_NODES / 4, 3), 256, 0, stream>>>(eidx, offs, elist, attbuf,
                                                    tabs, sbuf, alphabuf);
    k_out<<<dim3(12500 / 4, 3), 256, 0, stream>>>(sbuf, alphabuf, proj, eW2, eb2,
                                                  theta, bias, out);
}

// Round 6
// 413.008 us; speedup vs baseline: 2.4008x; 1.1264x over previous
//
#include <hip/hip_runtime.h>
#include <hip/hip_bf16.h>

#define N_NODES 50000
#define N_EDGES 200000
#define IN_F 128
#define HEADS 4
#define FD 64
#define HF 256
#define NCOLS 1536
#define NT3 (3 * N_NODES)          // 150000 segment rows (t-major)
#define E3  (3 * N_EDGES)          // 600000 slots
#define TROW 320                   // 5*64 bf16 per (node,head)

// ---- ws byte offsets ----
#define OFF_PROJ   0UL
#define OFF_TABS   51200000UL
#define OFF_ATT    179200000UL
#define OFF_RANK   182400000UL
#define OFF_ELIST  184800000UL
#define OFF_CNT    187200000UL
#define OFF_OFFS   187800000UL
#define OFF_BSUM   188400008UL
#define OFF_BSW    188401040UL
#define OFF_CB     188794256UL

typedef __attribute__((ext_vector_type(8))) short short8;
typedef __attribute__((ext_vector_type(4))) float f32x4;

__device__ inline short bf16_of(float x) {
    __hip_bfloat16 h = __float2bfloat16(x);
    return *reinterpret_cast<short*>(&h);
}
__device__ inline unsigned pack2(float lo, float hi) {
    return ((unsigned)(unsigned short)bf16_of(hi) << 16) |
           (unsigned)(unsigned short)bf16_of(lo);
}
__device__ inline short8 pack8(float4 a, float4 b) {
    short8 o;
    o[0] = bf16_of(a.x); o[1] = bf16_of(a.y); o[2] = bf16_of(a.z); o[3] = bf16_of(a.w);
    o[4] = bf16_of(b.x); o[5] = bf16_of(b.y); o[6] = bf16_of(b.z); o[7] = bf16_of(b.w);
    return o;
}
__device__ inline void unpk(uint4 v, float* f) {
    f[0] = __uint_as_float(v.x << 16); f[1] = __uint_as_float(v.x & 0xffff0000u);
    f[2] = __uint_as_float(v.y << 16); f[3] = __uint_as_float(v.y & 0xffff0000u);
    f[4] = __uint_as_float(v.z << 16); f[5] = __uint_as_float(v.z & 0xffff0000u);
    f[6] = __uint_as_float(v.w << 16); f[7] = __uint_as_float(v.w & 0xffff0000u);
}
__device__ inline float score8(uint4 ua, uint4 ub, uint4 uc, const float* w) {
    float fa[8], fb[8], fc[8]; unpk(ua, fa); unpk(ub, fb); unpk(uc, fc);
    float p = 0.f;
#pragma unroll
    for (int j = 0; j < 8; ++j) {
        float x = fa[j] + fb[j] + fc[j];
        x = fmaxf(x, 0.f);
        p = fmaf(x, w[j], p);
    }
    return p;
}

// ---------------------------------------------------------------------------
// K0: compose weights (table_W1 · W_proj_head) -> pre-swizzled B-frags + colbias
// ---------------------------------------------------------------------------
__global__ __launch_bounds__(128) void k_comp(const float* __restrict__ Wp,
                                              const float* __restrict__ attW1,
                                              const float* __restrict__ eW1,
                                              const float* __restrict__ attb1,
                                              const float* __restrict__ eb1,
                                              __hip_bfloat16* __restrict__ Bsw,
                                              float* __restrict__ colbias) {
    const int c = blockIdx.x;
    const int k = threadIdx.x;
    float acc;
    float cb = 0.f;
    if (c < HF) {
        acc = Wp[c * IN_F + k];
    } else {
        const int t = (c - HF) >> 8;
        const int rem = (c - HF) & 255;
        const int h = rem >> 6, g = rem & 63;
        const float* T;
        if (t == 0)      T = attW1 + g * 192;
        else if (t == 1) T = attW1 + g * 192 + 64;
        else if (t == 2) T = attW1 + g * 192 + 128;
        else if (t == 3) T = eW1 + g * 128;
        else             T = eW1 + g * 128 + 64;
        acc = 0.f;
        for (int f = 0; f < 64; ++f)
            acc += T[f] * Wp[(h * 64 + f) * IN_F + k];
        if (t == 0) cb = attb1[g];
        else if (t == 3) cb = eb1[g];
    }
    const int ct = c >> 4, cin = c & 15, kin = k & 31, j = k & 7;
    const int ks = k >> 5;
    const int l = cin + ((kin >> 3) << 4);
    Bsw[((ct * 4 + ks) * 64 + l) * 8 + j] = __float2bfloat16(acc);
    if (k == 0) colbias[c] = cb;
}

// ---------------------------------------------------------------------------
// K1: [50000x128] @ [128x1536] MFMA GEMM -> proj f32 + packed bf16 tables
// tabs layout: ((node*4 + h)*5 + t)*64 + g
// ---------------------------------------------------------------------------
__global__ __launch_bounds__(256) void k_tab(const float* __restrict__ in,
                                             const __hip_bfloat16* __restrict__ BswH,
                                             const float* __restrict__ colbias,
                                             float* __restrict__ proj,
                                             __hip_bfloat16* __restrict__ tabs) {
    const short8* Bsw = reinterpret_cast<const short8*>(BswH);
    const int lane = threadIdx.x & 63;
    const int wv = threadIdx.x >> 6;
    const int r = lane & 15, q = lane >> 4;
    const int row0 = blockIdx.x * 16;

    short8 a[4];
    const float* ip = in + (size_t)(row0 + r) * IN_F + q * 8;
#pragma unroll
    for (int ks = 0; ks < 4; ++ks)
        a[ks] = pack8(*(const float4*)(ip + ks * 32), *(const float4*)(ip + ks * 32 + 4));

    for (int ctl = 0; ctl < 24; ++ctl) {
        const int ct = wv * 24 + ctl;
        const int c = ct * 16 + r;
        const float cb = colbias[c];
        f32x4 acc = {cb, cb, cb, cb};
#pragma unroll
        for (int ks = 0; ks < 4; ++ks)
            acc = __builtin_amdgcn_mfma_f32_16x16x32_bf16(a[ks], Bsw[(ct * 4 + ks) * 64 + lane], acc, 0, 0, 0);
        if (c < HF) {
#pragma unroll
            for (int i = 0; i < 4; ++i)
                proj[(size_t)(row0 + q * 4 + i) * HF + c] = acc[i];
        } else {
            const int t = (c - HF) >> 8;
            const int rem = (c - HF) & 255;
            const int h = rem >> 6, g = rem & 63;
#pragma unroll
            for (int i = 0; i < 4; ++i)
                tabs[(((size_t)(row0 + q * 4 + i) * HEADS + h) * 5 + t) * 64 + g] =
                    __float2bfloat16(acc[i]);
        }
    }
}

// ---------------------------------------------------------------------------
// Sort chain: hist -> scan (3 kernels) -> scatter edge ids
// ---------------------------------------------------------------------------
__global__ __launch_bounds__(256) void k_hist(const int* __restrict__ eidx,
                                              int* __restrict__ cnt,
                                              int* __restrict__ rank) {
    const int g = blockIdx.x * 256 + threadIdx.x;
    if (g < E3) {
        const int node = eidx[g];
        const int t = g / N_EDGES;
        rank[g] = atomicAdd(&cnt[t * N_NODES + node], 1);
    }
}

__global__ __launch_bounds__(256) void k_scan1(const int* __restrict__ cnt,
                                               int* __restrict__ offs,
                                               int* __restrict__ bsums) {
    __shared__ int lds[256];
    const int b = blockIdx.x, t = threadIdx.x;
    const int base = b * 1024 + t * 4;
    int v[4];
#pragma unroll
    for (int c = 0; c < 4; ++c) v[c] = (base + c < NT3) ? cnt[base + c] : 0;
    const int s = v[0] + v[1] + v[2] + v[3];
    lds[t] = s;
    __syncthreads();
    for (int off = 1; off < 256; off <<= 1) {
        int x = (t >= off) ? lds[t - off] : 0;
        __syncthreads();
        lds[t] += x;
        __syncthreads();
    }
    if (t == 255) bsums[b] = lds[255];
    int run = lds[t] - s;
#pragma unroll
    for (int c = 0; c < 4; ++c) {
        if (base + c < NT3) offs[base + c] = run;
        run += v[c];
    }
}

__global__ __launch_bounds__(256) void k_scan2(int* __restrict__ bsums, int nb) {
    __shared__ int lds[256];
    const int t = threadIdx.x;
    const int v = (t < nb) ? bsums[t] : 0;
    lds[t] = v;
    __syncthreads();
    for (int off = 1; off < 256; off <<= 1) {
        int x = (t >= off) ? lds[t - off] : 0;
        __syncthreads();
        lds[t] += x;
        __syncthreads();
    }
    if (t < nb) bsums[t] = lds[t] - v;
}

__global__ __launch_bounds__(256) void k_scan3(int* __restrict__ offs,
                                               const int* __restrict__ bsums) {
    const int i = blockIdx.x * 256 + threadIdx.x;
    if (i < NT3) offs[i] += bsums[i >> 10];
    if (i == NT3) offs[NT3] = E3;
}

__global__ __launch_bounds__(256) void k_scat(const int* __restrict__ eidx,
                                              const int* __restrict__ offs,
                                              const int* __restrict__ rank,
                                              int* __restrict__ elist) {
    const int g = blockIdx.x * 256 + threadIdx.x;
    if (g < E3) {
        const int node = eidx[g];
        const int t = g / N_EDGES;
        const int e = g - t * N_EDGES;
        elist[offs[t * N_NODES + node] + rank[g]] = e;
    }
}

// ---------------------------------------------------------------------------
// K2: attention scores -> attbuf[e][4]. Block = 16 edges x 4 waves (wave=head).
// ---------------------------------------------------------------------------
__global__ __launch_bounds__(256) void k_att(
        const int* __restrict__ eidx,
        const __hip_bfloat16* __restrict__ tabs,
        const float* __restrict__ attW2, const float* __restrict__ attb2,
        float* __restrict__ attbuf) {
    __shared__ float s_lds[HEADS][16];
    const int lane = threadIdx.x & 63;
    const int h = threadIdx.x >> 6;
    const int r = lane & 15, q = lane >> 4;
    const int e0 = blockIdx.x * 16;

    float awlo[8], awhi[8];
    {
        float4 w0 = *(const float4*)(attW2 + q * 8);
        float4 w1 = *(const float4*)(attW2 + q * 8 + 4);
        awlo[0] = w0.x; awlo[1] = w0.y; awlo[2] = w0.z; awlo[3] = w0.w;
        awlo[4] = w1.x; awlo[5] = w1.y; awlo[6] = w1.z; awlo[7] = w1.w;
        float4 w2 = *(const float4*)(attW2 + 32 + q * 8);
        float4 w3 = *(const float4*)(attW2 + 32 + q * 8 + 4);
        awhi[0] = w2.x; awhi[1] = w2.y; awhi[2] = w2.z; awhi[3] = w2.w;
        awhi[4] = w3.x; awhi[5] = w3.y; awhi[6] = w3.z; awhi[7] = w3.w;
    }
    const float ab2s = attb2[0];

    const int ni = eidx[e0 + r];
    const int nj = eidx[N_EDGES + e0 + r];
    const int nk = eidx[2 * N_EDGES + e0 + r];

    const size_t bi = ((size_t)ni * HEADS + h) * TROW + q * 8;
    const size_t bj = ((size_t)nj * HEADS + h) * TROW + q * 8;
    const size_t bk = ((size_t)nk * HEADS + h) * TROW + q * 8;

    uint4 a0 = *(const uint4*)(tabs + bi);
    uint4 a1 = *(const uint4*)(tabs + bi + 32);
    uint4 b0 = *(const uint4*)(tabs + bj + 64);
    uint4 b1 = *(const uint4*)(tabs + bj + 96);
    uint4 c0 = *(const uint4*)(tabs + bk + 128);
    uint4 c1 = *(const uint4*)(tabs + bk + 160);

    float p = score8(a0, b0, c0, awlo) + score8(a1, b1, c1, awhi);
    p += __shfl_xor(p, 16);
    p += __shfl_xor(p, 32);
    float sc = p + ab2s;
    sc = fmaxf(sc, 0.2f * sc);
    if (lane < 16) s_lds[h][lane] = sc;
    __syncthreads();
    if (lane < 16) {
        const float s0 = s_lds[0][lane], s1 = s_lds[1][lane];
        const float s2 = s_lds[2][lane], s3 = s_lds[3][lane];
        const float mx = fmaxf(fmaxf(s0, s1), fmaxf(s2, s3));
        const float x0 = __expf(s0 - mx), x1 = __expf(s1 - mx);
        const float x2 = __expf(s2 - mx), x3 = __expf(s3 - mx);
        const float rs = 1.f / (x0 + x1 + x2 + x3);
        const float xh = (h == 0) ? x0 : (h == 1) ? x1 : (h == 2) ? x2 : x3;
        attbuf[(size_t)(e0 + lane) * 4 + h] = xh * rs;
    }
}

// ---------------------------------------------------------------------------
// K3 (fused): segment-sum + W2 GEMM + elu epilogue.
// Block = 4 nodes (one t) x 4 waves. Phase 1: wave w accumulates node n0+w
// (lane = (h,r), 4 cols/lane). Phase 2: 16 rho-rows -> LDS A-tile, wave w
// computes f-block ct=w via 2 MFMAs, D staged in LDS. Phase 3: cooperative
// float4 epilogue (proj/theta/bias/alpha*b2 + elu), dense 4 KB store.
// ---------------------------------------------------------------------------
__global__ __launch_bounds__(256) void k_seg(const int* __restrict__ eidx,
                                             const int* __restrict__ offs,
                                             const int* __restrict__ elist,
                                             const float* __restrict__ attbuf,
                                             const __hip_bfloat16* __restrict__ tabs,
                                             const float* __restrict__ proj,
                                             const float* __restrict__ eW2,
                                             const float* __restrict__ eb2,
                                             const float* __restrict__ theta,
                                             const float* __restrict__ bias,
                                             float* __restrict__ out) {
    __shared__ __hip_bfloat16 S_lds[16][72];   // padded: stride 144 B
    __shared__ float a_lds[16];
    __shared__ float D_lds[16][68];            // padded: stride 272 B

    const int lane = threadIdx.x & 63;
    const int w = threadIdx.x >> 6;
    const int h = lane >> 4, r = lane & 15;
    const int q = lane >> 4;                   // MFMA quad index (phase 2)
    const int t = blockIdx.y;
    const int n0 = blockIdx.x * 4;
    const int n = n0 + w;
    const int idx = t * N_NODES + n;
    const int p0 = offs[idx], p1 = offs[idx + 1];
    int s0, s1;
    if (t == 0)      { s0 = 1; s1 = 2; }
    else if (t == 1) { s0 = 0; s1 = 2; }
    else             { s0 = 0; s1 = 1; }

    // ---- phase 1: per-wave segment accumulation ----
    float acc0 = 0.f, acc1 = 0.f, acc2 = 0.f, acc3 = 0.f, alpha = 0.f;
    for (int p = p0; p < p1; ++p) {
        const int e = elist[p];
        const int x = eidx[s0 * N_EDGES + e];
        const int y = eidx[s1 * N_EDGES + e];
        const float at = attbuf[(size_t)e * 4 + h];
        const __hip_bfloat16* v1p = tabs + (((size_t)x * 4 + h) * 5 + 3) * 64;
        const __hip_bfloat16* v2p = tabs + (((size_t)y * 4 + h) * 5 + 4) * 64;
        const uint2 ua = *(const uint2*)(v1p + r * 4);
        const uint2 ub = *(const uint2*)(v2p + r * 4);
        float g0 = __uint_as_float(ua.x << 16) + __uint_as_float(ub.x << 16);
        float g1 = __uint_as_float(ua.x & 0xffff0000u) + __uint_as_float(ub.x & 0xffff0000u);
        float g2 = __uint_as_float(ua.y << 16) + __uint_as_float(ub.y << 16);
        float g3 = __uint_as_float(ua.y & 0xffff0000u) + __uint_as_float(ub.y & 0xffff0000u);
        g0 = fmaxf(g0, 0.2f * g0); g1 = fmaxf(g1, 0.2f * g1);
        g2 = fmaxf(g2, 0.2f * g2); g3 = fmaxf(g3, 0.2f * g3);
        acc0 = fmaf(at, g0, acc0); acc1 = fmaf(at, g1, acc1);
        acc2 = fmaf(at, g2, acc2); acc3 = fmaf(at, g3, acc3);
        alpha += at;
    }
    const int tr = w * 4 + h;                  // tile row; rho = idx4 base + tr
    uint2 st;
    st.x = pack2(acc0, acc1);
    st.y = pack2(acc2, acc3);
    *(uint2*)&S_lds[tr][r * 4] = st;
    if (r == 0) a_lds[tr] = alpha;
    __syncthreads();

    // ---- phase 2: wave w = output-feature block ct; D[i][f] to LDS ----
    {
        const float* wp0 = eW2 + (w * 16 + r) * FD + q * 8;
        const float* wp1 = eW2 + (w * 16 + r) * FD + 32 + q * 8;
        short8 bfr0 = pack8(*(const float4*)wp0, *(const float4*)(wp0 + 4));
        short8 bfr1 = pack8(*(const float4*)wp1, *(const float4*)(wp1 + 4));
        short8 A0 = *(short8*)&S_lds[r][q * 8];
        short8 A1 = *(short8*)&S_lds[r][32 + q * 8];
        f32x4 acc = {0.f, 0.f, 0.f, 0.f};
        acc = __builtin_amdgcn_mfma_f32_16x16x32_bf16(A0, bfr0, acc, 0, 0, 0);
        acc = __builtin_amdgcn_mfma_f32_16x16x32_bf16(A1, bfr1, acc, 0, 0, 0);
#pragma unroll
        for (int i = 0; i < 4; ++i)
            D_lds[q * 4 + i][w * 16 + r] = acc[i];
    }
    __syncthreads();

    // ---- phase 3: cooperative vectorized epilogue ----
    const int row = threadIdx.x >> 4;          // 0..15 tile row
    const int c4 = threadIdx.x & 15;           // f-chunk of 4
    const int f = c4 * 4;
    const int hh = row & 3;
    const int nn = n0 + (row >> 2);
    const size_t rho = ((size_t)t * N_NODES + nn) * 4 + hh;

    float4 Dv = *(float4*)&D_lds[row][f];
    float4 pj = *(const float4*)(proj + (size_t)nn * HF + hh * 64 + f);
    float4 th = *(const float4*)(theta + hh * 64 + f);
    float4 bi = *(const float4*)(bias + hh * 64 + f);
    float4 b2 = *(const float4*)(eb2 + f);
    const float al = a_lds[row];
    float4 o;
    float v;
    v = th.x * pj.x + Dv.x + al * b2.x + bi.x; o.x = v > 0.f ? v : expm1f(v);
    v = th.y * pj.y + Dv.y + al * b2.y + bi.y; o.y = v > 0.f ? v : expm1f(v);
    v = th.z * pj.z + Dv.z + al * b2.z + bi.z; o.z = v > 0.f ? v : expm1f(v);
    v = th.w * pj.w + Dv.w + al * b2.w + bi.w; o.w = v > 0.f ? v : expm1f(v);
    *(float4*)(out + rho * 64 + f) = o;
}

// ---------------------------------------------------------------------------
extern "C" void kernel_launch(void* const* d_in, const int* in_sizes, int n_in,
                              void* d_out, int out_size, void* d_ws, size_t ws_size,
                              hipStream_t stream) {
    const float* in_nodes = (const float*)d_in[0];
    const int*   eidx     = (const int*)d_in[1];
    const float* Wp       = (const float*)d_in[2];
    const float* attW1    = (const float*)d_in[3];
    const float* attb1    = (const float*)d_in[4];
    const float* attW2    = (const float*)d_in[5];
    const float* attb2    = (const float*)d_in[6];
    const float* eW1      = (const float*)d_in[7];
    const float* eb1      = (const float*)d_in[8];
    const float* eW2      = (const float*)d_in[9];
    const float* eb2      = (const float*)d_in[10];
    const float* theta    = (const float*)d_in[11];
    const float* bias     = (const float*)d_in[12];

    char* ws = (char*)d_ws;
    float*          proj     = (float*)(ws + OFF_PROJ);
    __hip_bfloat16* tabs     = (__hip_bfloat16*)(ws + OFF_TABS);
    float*          attbuf   = (float*)(ws + OFF_ATT);
    int*            rank     = (int*)(ws + OFF_RANK);
    int*            elist    = (int*)(ws + OFF_ELIST);
    int*            cnt      = (int*)(ws + OFF_CNT);
    int*            offs     = (int*)(ws + OFF_OFFS);
    int*            bsums    = (int*)(ws + OFF_BSUM);
    __hip_bfloat16* Bsw      = (__hip_bfloat16*)(ws + OFF_BSW);
    float*          colbias  = (float*)(ws + OFF_CB);

    float* out = (float*)d_out;

    (void)hipMemsetAsync(cnt, 0, NT3 * sizeof(int), stream);

    k_comp<<<NCOLS, 128, 0, stream>>>(Wp, attW1, eW1, attb1, eb1, Bsw, colbias);
    k_tab<<<N_NODES / 16, 256, 0, stream>>>(in_nodes, Bsw, colbias, proj, tabs);

    k_hist<<<(E3 + 255) / 256, 256, 0, stream>>>(eidx, cnt, rank);
    k_scan1<<<(NT3 + 1023) / 1024, 256, 0, stream>>>(cnt, offs, bsums);
    k_scan2<<<1, 256, 0, stream>>>(bsums, (NT3 + 1023) / 1024);
    k_scan3<<<(NT3 + 256) / 256, 256, 0, stream>>>(offs, bsums);
    k_scat<<<(E3 + 255) / 256, 256, 0, stream>>>(eidx, offs, rank, elist);

    k_att<<<N_EDGES / 16, 256, 0, stream>>>(eidx, tabs, attW2, attb2, attbuf);
    k_seg<<<dim3(N_NODES / 4, 3), 256, 0, stream>>>(eidx, offs, elist, attbuf,
                                                    tabs, proj, eW2, eb2,
                                                    theta, bias, out);
}

// Round 7
// 368.390 us; speedup vs baseline: 2.6916x; 1.1211x over previous
//
#include <hip/hip_runtime.h>
#include <hip/hip_bf16.h>

#define N_NODES 50000
#define N_EDGES 200000
#define IN_F 128
#define HEADS 4
#define FD 64
#define HF 256
#define NCOLS 1536
#define NT3 (3 * N_NODES)          // 150000 segment rows (t-major)
#define E3  (3 * N_EDGES)          // 600000 slots
#define TROW 320                   // 5*64 bf16 per (node,head)

// ---- ws byte offsets ----
#define OFF_PROJ   0UL
#define OFF_TABS   51200000UL
#define OFF_ATT    179200000UL
#define OFF_RANK   182400000UL
#define OFF_ELIST  184800000UL
#define OFF_CNT    187200000UL
#define OFF_OFFS   187800000UL
#define OFF_BSUM   188400008UL
#define OFF_BSW    188401040UL
#define OFF_CB     188794256UL

typedef __attribute__((ext_vector_type(8))) short short8;
typedef __attribute__((ext_vector_type(4))) float f32x4;

__device__ inline short bf16_of(float x) {
    __hip_bfloat16 h = __float2bfloat16(x);
    return *reinterpret_cast<short*>(&h);
}
__device__ inline unsigned pack2(float lo, float hi) {
    return ((unsigned)(unsigned short)bf16_of(hi) << 16) |
           (unsigned)(unsigned short)bf16_of(lo);
}
__device__ inline short8 pack8(float4 a, float4 b) {
    short8 o;
    o[0] = bf16_of(a.x); o[1] = bf16_of(a.y); o[2] = bf16_of(a.z); o[3] = bf16_of(a.w);
    o[4] = bf16_of(b.x); o[5] = bf16_of(b.y); o[6] = bf16_of(b.z); o[7] = bf16_of(b.w);
    return o;
}
__device__ inline void unpk(uint4 v, float* f) {
    f[0] = __uint_as_float(v.x << 16); f[1] = __uint_as_float(v.x & 0xffff0000u);
    f[2] = __uint_as_float(v.y << 16); f[3] = __uint_as_float(v.y & 0xffff0000u);
    f[4] = __uint_as_float(v.z << 16); f[5] = __uint_as_float(v.z & 0xffff0000u);
    f[6] = __uint_as_float(v.w << 16); f[7] = __uint_as_float(v.w & 0xffff0000u);
}
__device__ inline float score8(uint4 ua, uint4 ub, uint4 uc, const float* w) {
    float fa[8], fb[8], fc[8]; unpk(ua, fa); unpk(ub, fb); unpk(uc, fc);
    float p = 0.f;
#pragma unroll
    for (int j = 0; j < 8; ++j) {
        float x = fa[j] + fb[j] + fc[j];
        x = fmaxf(x, 0.f);
        p = fmaf(x, w[j], p);
    }
    return p;
}

// ---------------------------------------------------------------------------
// K0: compose weights (table_W1 · W_proj_head) -> pre-swizzled B-frags + colbias
// ---------------------------------------------------------------------------
__global__ __launch_bounds__(128) void k_comp(const float* __restrict__ Wp,
                                              const float* __restrict__ attW1,
                                              const float* __restrict__ eW1,
                                              const float* __restrict__ attb1,
                                              const float* __restrict__ eb1,
                                              __hip_bfloat16* __restrict__ Bsw,
                                              float* __restrict__ colbias) {
    const int c = blockIdx.x;
    const int k = threadIdx.x;
    float acc;
    float cb = 0.f;
    if (c < HF) {
        acc = Wp[c * IN_F + k];
    } else {
        const int t = (c - HF) >> 8;
        const int rem = (c - HF) & 255;
        const int h = rem >> 6, g = rem & 63;
        const float* T;
        if (t == 0)      T = attW1 + g * 192;
        else if (t == 1) T = attW1 + g * 192 + 64;
        else if (t == 2) T = attW1 + g * 192 + 128;
        else if (t == 3) T = eW1 + g * 128;
        else             T = eW1 + g * 128 + 64;
        acc = 0.f;
        for (int f = 0; f < 64; ++f)
            acc += T[f] * Wp[(h * 64 + f) * IN_F + k];
        if (t == 0) cb = attb1[g];
        else if (t == 3) cb = eb1[g];
    }
    const int ct = c >> 4, cin = c & 15, kin = k & 31, j = k & 7;
    const int ks = k >> 5;
    const int l = cin + ((kin >> 3) << 4);
    Bsw[((ct * 4 + ks) * 64 + l) * 8 + j] = __float2bfloat16(acc);
    if (k == 0) colbias[c] = cb;
}

// ---------------------------------------------------------------------------
// K1: [50000x128] @ [128x1536] MFMA GEMM -> proj f32 + packed bf16 tables
// tabs layout: ((node*4 + h)*5 + t)*64 + g
// ---------------------------------------------------------------------------
__global__ __launch_bounds__(256) void k_tab(const float* __restrict__ in,
                                             const __hip_bfloat16* __restrict__ BswH,
                                             const float* __restrict__ colbias,
                                             float* __restrict__ proj,
                                             __hip_bfloat16* __restrict__ tabs) {
    const short8* Bsw = reinterpret_cast<const short8*>(BswH);
    const int lane = threadIdx.x & 63;
    const int wv = threadIdx.x >> 6;
    const int r = lane & 15, q = lane >> 4;
    const int row0 = blockIdx.x * 16;

    short8 a[4];
    const float* ip = in + (size_t)(row0 + r) * IN_F + q * 8;
#pragma unroll
    for (int ks = 0; ks < 4; ++ks)
        a[ks] = pack8(*(const float4*)(ip + ks * 32), *(const float4*)(ip + ks * 32 + 4));

    for (int ctl = 0; ctl < 24; ++ctl) {
        const int ct = wv * 24 + ctl;
        const int c = ct * 16 + r;
        const float cb = colbias[c];
        f32x4 acc = {cb, cb, cb, cb};
#pragma unroll
        for (int ks = 0; ks < 4; ++ks)
            acc = __builtin_amdgcn_mfma_f32_16x16x32_bf16(a[ks], Bsw[(ct * 4 + ks) * 64 + lane], acc, 0, 0, 0);
        if (c < HF) {
#pragma unroll
            for (int i = 0; i < 4; ++i)
                proj[(size_t)(row0 + q * 4 + i) * HF + c] = acc[i];
        } else {
            const int t = (c - HF) >> 8;
            const int rem = (c - HF) & 255;
            const int h = rem >> 6, g = rem & 63;
#pragma unroll
            for (int i = 0; i < 4; ++i)
                tabs[(((size_t)(row0 + q * 4 + i) * HEADS + h) * 5 + t) * 64 + g] =
                    __float2bfloat16(acc[i]);
        }
    }
}

// ---------------------------------------------------------------------------
// Sort chain: hist -> scan (3 kernels) -> scatter edge ids
// ---------------------------------------------------------------------------
__global__ __launch_bounds__(256) void k_hist(const int* __restrict__ eidx,
                                              int* __restrict__ cnt,
                                              int* __restrict__ rank) {
    const int g = blockIdx.x * 256 + threadIdx.x;
    if (g < E3) {
        const int node = eidx[g];
        const int t = g / N_EDGES;
        rank[g] = atomicAdd(&cnt[t * N_NODES + node], 1);
    }
}

__global__ __launch_bounds__(256) void k_scan1(const int* __restrict__ cnt,
                                               int* __restrict__ offs,
                                               int* __restrict__ bsums) {
    __shared__ int lds[256];
    const int b = blockIdx.x, t = threadIdx.x;
    const int base = b * 1024 + t * 4;
    int v[4];
#pragma unroll
    for (int c = 0; c < 4; ++c) v[c] = (base + c < NT3) ? cnt[base + c] : 0;
    const int s = v[0] + v[1] + v[2] + v[3];
    lds[t] = s;
    __syncthreads();
    for (int off = 1; off < 256; off <<= 1) {
        int x = (t >= off) ? lds[t - off] : 0;
        __syncthreads();
        lds[t] += x;
        __syncthreads();
    }
    if (t == 255) bsums[b] = lds[255];
    int run = lds[t] - s;
#pragma unroll
    for (int c = 0; c < 4; ++c) {
        if (base + c < NT3) offs[base + c] = run;
        run += v[c];
    }
}

__global__ __launch_bounds__(256) void k_scan2(int* __restrict__ bsums, int nb) {
    __shared__ int lds[256];
    const int t = threadIdx.x;
    const int v = (t < nb) ? bsums[t] : 0;
    lds[t] = v;
    __syncthreads();
    for (int off = 1; off < 256; off <<= 1) {
        int x = (t >= off) ? lds[t - off] : 0;
        __syncthreads();
        lds[t] += x;
        __syncthreads();
    }
    if (t < nb) bsums[t] = lds[t] - v;
}

__global__ __launch_bounds__(256) void k_scan3(int* __restrict__ offs,
                                               const int* __restrict__ bsums) {
    const int i = blockIdx.x * 256 + threadIdx.x;
    if (i < NT3) offs[i] += bsums[i >> 10];
    if (i == NT3) offs[NT3] = E3;
}

__global__ __launch_bounds__(256) void k_scat(const int* __restrict__ eidx,
                                              const int* __restrict__ offs,
                                              const int* __restrict__ rank,
                                              int* __restrict__ elist) {
    const int g = blockIdx.x * 256 + threadIdx.x;
    if (g < E3) {
        const int node = eidx[g];
        const int t = g / N_EDGES;
        const int e = g - t * N_EDGES;
        elist[offs[t * N_NODES + node] + rank[g]] = e;
    }
}

// ---------------------------------------------------------------------------
// K2: attention scores -> attbuf[e][4]. Block = 16 edges x 4 waves (wave=head).
// ---------------------------------------------------------------------------
__global__ __launch_bounds__(256) void k_att(
        const int* __restrict__ eidx,
        const __hip_bfloat16* __restrict__ tabs,
        const float* __restrict__ attW2, const float* __restrict__ attb2,
        float* __restrict__ attbuf) {
    __shared__ float s_lds[HEADS][16];
    const int lane = threadIdx.x & 63;
    const int h = threadIdx.x >> 6;
    const int r = lane & 15, q = lane >> 4;
    const int e0 = blockIdx.x * 16;

    float awlo[8], awhi[8];
    {
        float4 w0 = *(const float4*)(attW2 + q * 8);
        float4 w1 = *(const float4*)(attW2 + q * 8 + 4);
        awlo[0] = w0.x; awlo[1] = w0.y; awlo[2] = w0.z; awlo[3] = w0.w;
        awlo[4] = w1.x; awlo[5] = w1.y; awlo[6] = w1.z; awlo[7] = w1.w;
        float4 w2 = *(const float4*)(attW2 + 32 + q * 8);
        float4 w3 = *(const float4*)(attW2 + 32 + q * 8 + 4);
        awhi[0] = w2.x; awhi[1] = w2.y; awhi[2] = w2.z; awhi[3] = w2.w;
        awhi[4] = w3.x; awhi[5] = w3.y; awhi[6] = w3.z; awhi[7] = w3.w;
    }
    const float ab2s = attb2[0];

    const int ni = eidx[e0 + r];
    const int nj = eidx[N_EDGES + e0 + r];
    const int nk = eidx[2 * N_EDGES + e0 + r];

    const size_t bi = ((size_t)ni * HEADS + h) * TROW + q * 8;
    const size_t bj = ((size_t)nj * HEADS + h) * TROW + q * 8;
    const size_t bk = ((size_t)nk * HEADS + h) * TROW + q * 8;

    uint4 a0 = *(const uint4*)(tabs + bi);
    uint4 a1 = *(const uint4*)(tabs + bi + 32);
    uint4 b0 = *(const uint4*)(tabs + bj + 64);
    uint4 b1 = *(const uint4*)(tabs + bj + 96);
    uint4 c0 = *(const uint4*)(tabs + bk + 128);
    uint4 c1 = *(const uint4*)(tabs + bk + 160);

    float p = score8(a0, b0, c0, awlo) + score8(a1, b1, c1, awhi);
    p += __shfl_xor(p, 16);
    p += __shfl_xor(p, 32);
    float sc = p + ab2s;
    sc = fmaxf(sc, 0.2f * sc);
    if (lane < 16) s_lds[h][lane] = sc;
    __syncthreads();
    if (lane < 16) {
        const float s0 = s_lds[0][lane], s1 = s_lds[1][lane];
        const float s2 = s_lds[2][lane], s3 = s_lds[3][lane];
        const float mx = fmaxf(fmaxf(s0, s1), fmaxf(s2, s3));
        const float x0 = __expf(s0 - mx), x1 = __expf(s1 - mx);
        const float x2 = __expf(s2 - mx), x3 = __expf(s3 - mx);
        const float rs = 1.f / (x0 + x1 + x2 + x3);
        const float xh = (h == 0) ? x0 : (h == 1) ? x1 : (h == 2) ? x2 : x3;
        attbuf[(size_t)(e0 + lane) * 4 + h] = xh * rs;
    }
}

// ---------------------------------------------------------------------------
// K3 (fused): segment-sum + W2 GEMM + elu epilogue.
// Phase 1 processes edges in 4-wide chunks: all loads of a chunk issued
// before any dependent math -> 4-8-way memory-level parallelism instead of
// a serial per-edge miss chain (k_seg was 2.67 TB/s, latency-bound).
// ---------------------------------------------------------------------------
__global__ __launch_bounds__(256) void k_seg(const int* __restrict__ eidx,
                                             const int* __restrict__ offs,
                                             const int* __restrict__ elist,
                                             const float* __restrict__ attbuf,
                                             const __hip_bfloat16* __restrict__ tabs,
                                             const float* __restrict__ proj,
                                             const float* __restrict__ eW2,
                                             const float* __restrict__ eb2,
                                             const float* __restrict__ theta,
                                             const float* __restrict__ bias,
                                             float* __restrict__ out) {
    __shared__ __hip_bfloat16 S_lds[16][72];   // padded: stride 144 B
    __shared__ float a_lds[16];
    __shared__ float D_lds[16][68];            // padded: stride 272 B

    const int lane = threadIdx.x & 63;
    const int w = threadIdx.x >> 6;
    const int h = lane >> 4, r = lane & 15;
    const int q = lane >> 4;                   // MFMA quad index (phase 2)
    const int t = blockIdx.y;
    const int n0 = blockIdx.x * 4;
    const int n = n0 + w;
    const int idx = t * N_NODES + n;
    const int p0 = offs[idx], p1 = offs[idx + 1];
    int s0, s1;
    if (t == 0)      { s0 = 1; s1 = 2; }
    else if (t == 1) { s0 = 0; s1 = 2; }
    else             { s0 = 0; s1 = 1; }

    // ---- phase 1: 4-wide batched segment accumulation ----
    float acc0 = 0.f, acc1 = 0.f, acc2 = 0.f, acc3 = 0.f, alpha = 0.f;
    for (int base = p0; base < p1; base += 4) {
        int ee[4];
#pragma unroll
        for (int c = 0; c < 4; ++c) {
            const int p = base + c;
            ee[c] = elist[p < p1 ? p : p1 - 1];    // clamp: stays in-segment
        }
        int xx[4], yy[4];
        float at[4];
#pragma unroll
        for (int c = 0; c < 4; ++c) {
            xx[c] = eidx[s0 * N_EDGES + ee[c]];
            yy[c] = eidx[s1 * N_EDGES + ee[c]];
        }
#pragma unroll
        for (int c = 0; c < 4; ++c)
            at[c] = (base + c < p1) ? attbuf[(size_t)ee[c] * 4 + h] : 0.f;
        uint2 ua[4], ub[4];
#pragma unroll
        for (int c = 0; c < 4; ++c) {
            ua[c] = *(const uint2*)(tabs + (((size_t)xx[c] * 4 + h) * 5 + 3) * 64 + r * 4);
            ub[c] = *(const uint2*)(tabs + (((size_t)yy[c] * 4 + h) * 5 + 4) * 64 + r * 4);
        }
#pragma unroll
        for (int c = 0; c < 4; ++c) {
            float g0 = __uint_as_float(ua[c].x << 16) + __uint_as_float(ub[c].x << 16);
            float g1 = __uint_as_float(ua[c].x & 0xffff0000u) + __uint_as_float(ub[c].x & 0xffff0000u);
            float g2 = __uint_as_float(ua[c].y << 16) + __uint_as_float(ub[c].y << 16);
            float g3 = __uint_as_float(ua[c].y & 0xffff0000u) + __uint_as_float(ub[c].y & 0xffff0000u);
            g0 = fmaxf(g0, 0.2f * g0); g1 = fmaxf(g1, 0.2f * g1);
            g2 = fmaxf(g2, 0.2f * g2); g3 = fmaxf(g3, 0.2f * g3);
            acc0 = fmaf(at[c], g0, acc0); acc1 = fmaf(at[c], g1, acc1);
            acc2 = fmaf(at[c], g2, acc2); acc3 = fmaf(at[c], g3, acc3);
            alpha += at[c];
        }
    }
    const int tr = w * 4 + h;                  // tile row
    uint2 st;
    st.x = pack2(acc0, acc1);
    st.y = pack2(acc2, acc3);
    *(uint2*)&S_lds[tr][r * 4] = st;
    if (r == 0) a_lds[tr] = alpha;
    __syncthreads();

    // ---- phase 2: wave w = output-feature block ct; D[i][f] to LDS ----
    {
        const float* wp0 = eW2 + (w * 16 + r) * FD + q * 8;
        const float* wp1 = eW2 + (w * 16 + r) * FD + 32 + q * 8;
        short8 bfr0 = pack8(*(const float4*)wp0, *(const float4*)(wp0 + 4));
        short8 bfr1 = pack8(*(const float4*)wp1, *(const float4*)(wp1 + 4));
        short8 A0 = *(short8*)&S_lds[r][q * 8];
        short8 A1 = *(short8*)&S_lds[r][32 + q * 8];
        f32x4 acc = {0.f, 0.f, 0.f, 0.f};
        acc = __builtin_amdgcn_mfma_f32_16x16x32_bf16(A0, bfr0, acc, 0, 0, 0);
        acc = __builtin_amdgcn_mfma_f32_16x16x32_bf16(A1, bfr1, acc, 0, 0, 0);
#pragma unroll
        for (int i = 0; i < 4; ++i)
            D_lds[q * 4 + i][w * 16 + r] = acc[i];
    }
    __syncthreads();

    // ---- phase 3: cooperative vectorized epilogue ----
    const int row = threadIdx.x >> 4;          // 0..15 tile row
    const int c4 = threadIdx.x & 15;           // f-chunk of 4
    const int f = c4 * 4;
    const int hh = row & 3;
    const int nn = n0 + (row >> 2);
    const size_t rho = ((size_t)t * N_NODES + nn) * 4 + hh;

    float4 Dv = *(float4*)&D_lds[row][f];
    float4 pj = *(const float4*)(proj + (size_t)nn * HF + hh * 64 + f);
    float4 th = *(const float4*)(theta + hh * 64 + f);
    float4 bi = *(const float4*)(bias + hh * 64 + f);
    float4 b2 = *(const float4*)(eb2 + f);
    const float al = a_lds[row];
    float4 o;
    float v;
    v = th.x * pj.x + Dv.x + al * b2.x + bi.x; o.x = v > 0.f ? v : expm1f(v);
    v = th.y * pj.y + Dv.y + al * b2.y + bi.y; o.y = v > 0.f ? v : expm1f(v);
    v = th.z * pj.z + Dv.z + al * b2.z + bi.z; o.z = v > 0.f ? v : expm1f(v);
    v = th.w * pj.w + Dv.w + al * b2.w + bi.w; o.w = v > 0.f ? v : expm1f(v);
    *(float4*)(out + rho * 64 + f) = o;
}

// ---------------------------------------------------------------------------
extern "C" void kernel_launch(void* const* d_in, const int* in_sizes, int n_in,
                              void* d_out, int out_size, void* d_ws, size_t ws_size,
                              hipStream_t stream) {
    const float* in_nodes = (const float*)d_in[0];
    const int*   eidx     = (const int*)d_in[1];
    const float* Wp       = (const float*)d_in[2];
    const float* attW1    = (const float*)d_in[3];
    const float* attb1    = (const float*)d_in[4];
    const float* attW2    = (const float*)d_in[5];
    const float* attb2    = (const float*)d_in[6];
    const float* eW1      = (const float*)d_in[7];
    const float* eb1      = (const float*)d_in[8];
    const float* eW2      = (const float*)d_in[9];
    const float* eb2      = (const float*)d_in[10];
    const float* theta    = (const float*)d_in[11];
    const float* bias     = (const float*)d_in[12];

    char* ws = (char*)d_ws;
    float*          proj     = (float*)(ws + OFF_PROJ);
    __hip_bfloat16* tabs     = (__hip_bfloat16*)(ws + OFF_TABS);
    float*          attbuf   = (float*)(ws + OFF_ATT);
    int*            rank     = (int*)(ws + OFF_RANK);
    int*            elist    = (int*)(ws + OFF_ELIST);
    int*            cnt      = (int*)(ws + OFF_CNT);
    int*            offs     = (int*)(ws + OFF_OFFS);
    int*            bsums    = (int*)(ws + OFF_BSUM);
    __hip_bfloat16* Bsw      = (__hip_bfloat16*)(ws + OFF_BSW);
    float*          colbias  = (float*)(ws + OFF_CB);

    float* out = (float*)d_out;

    (void)hipMemsetAsync(cnt, 0, NT3 * sizeof(int), stream);

    k_comp<<<NCOLS, 128, 0, stream>>>(Wp, attW1, eW1, attb1, eb1, Bsw, colbias);
    k_tab<<<N_NODES / 16, 256, 0, stream>>>(in_nodes, Bsw, colbias, proj, tabs);

    k_hist<<<(E3 + 255) / 256, 256, 0, stream>>>(eidx, cnt, rank);
    k_scan1<<<(NT3 + 1023) / 1024, 256, 0, stream>>>(cnt, offs, bsums);
    k_scan2<<<1, 256, 0, stream>>>(bsums, (NT3 + 1023) / 1024);
    k_scan3<<<(NT3 + 256) / 256, 256, 0, stream>>>(offs, bsums);
    k_scat<<<(E3 + 255) / 256, 256, 0, stream>>>(eidx, offs, rank, elist);

    k_att<<<N_EDGES / 16, 256, 0, stream>>>(eidx, tabs, attW2, attb2, attbuf);
    k_seg<<<dim3(N_NODES / 4, 3), 256, 0, stream>>>(eidx, offs, elist, attbuf,
                                                    tabs, proj, eW2, eb2,
                                                    theta, bias, out);
}